// Round 4
// baseline (185.487 us; speedup 1.0000x reference)
//
#include <hip/hip_runtime.h>
#include <cstdint>
#include <cstddef>

#define B_DIM 8
#define U_DIM 1024
#define SD    1024                 // SIZE == D_ATT == 1024
#define M_DIM (B_DIM * U_DIM)      // 8192 rows; also B*D channel count
#define NC 32                      // scan chunks
#define CT 32                      // tokens per chunk (NC*CT == U_DIM)

typedef __attribute__((ext_vector_type(8))) short short8;
typedef __attribute__((ext_vector_type(4))) float f32x4;

typedef __attribute__((address_space(3))) void       lds_t;
typedef const __attribute__((address_space(1))) void glb_t;

__device__ __forceinline__ ushort f2bf(float f) {
    union { float f; uint32_t u; } c; c.f = f;
    uint32_t r = (c.u + 0x7FFFu + ((c.u >> 16) & 1u)) >> 16;   // RNE
    return (ushort)r;
}
__device__ __forceinline__ float bf2f(ushort h) {
    union { float f; uint32_t u; } c; c.u = ((uint32_t)h) << 16; return c.f;
}

// ---------------- prepass: W[K][N] f32 -> W^T[N][K] bf16, 4 matrices ----------------
__global__ __launch_bounds__(256)
void wtrans_kernel(const float* __restrict__ Wk, const float* __restrict__ Wv,
                   const float* __restrict__ Wr, const float* __restrict__ Wo,
                   ushort* __restrict__ WT)
{
    __shared__ float t[32][33];
    const float* W = (blockIdx.z == 0) ? Wk : (blockIdx.z == 1) ? Wv
                   : (blockIdx.z == 2) ? Wr : Wo;
    ushort* o = WT + (size_t)blockIdx.z * SD * SD;
    const int tx = threadIdx.x & 31, ty = threadIdx.x >> 5;
    const int k0 = blockIdx.y * 32, n0 = blockIdx.x * 32;
    #pragma unroll
    for (int i = 0; i < 4; ++i)
        t[ty + i * 8][tx] = W[(size_t)(k0 + ty + i * 8) * SD + n0 + tx];
    __syncthreads();
    #pragma unroll
    for (int i = 0; i < 4; ++i)
        o[(size_t)(n0 + ty + i * 8) * SD + k0 + tx] = f2bf(t[tx][ty + i * 8]);
}

// ---------------- prepass: A_j = sh + mix_j*(x - sh), bf16, all three in one pass ----
__global__ __launch_bounds__(256)
void mix3_kernel(const float* __restrict__ x,
                 const float* __restrict__ mk, const float* __restrict__ mv,
                 const float* __restrict__ mr,
                 ushort* __restrict__ Ak, ushort* __restrict__ Av,
                 ushort* __restrict__ Ar)
{
    const int idx = blockIdx.x * 256 + threadIdx.x;  // 2M groups of 4
    const int m = idx >> 8;
    const int s = (idx & 255) << 2;
    const float4 xv = *(const float4*)&x[(size_t)m * SD + s];
    float4 sh = make_float4(0.f, 0.f, 0.f, 0.f);
    if (m & (U_DIM - 1)) sh = *(const float4*)&x[(size_t)(m - 1) * SD + s];
    const float4 dx = make_float4(xv.x - sh.x, xv.y - sh.y, xv.z - sh.z, xv.w - sh.w);
    const size_t off = (size_t)m * SD + s;

    float4 mx;
    ushort4 o;
    mx = *(const float4*)&mk[s];
    o.x = f2bf(sh.x + mx.x * dx.x); o.y = f2bf(sh.y + mx.y * dx.y);
    o.z = f2bf(sh.z + mx.z * dx.z); o.w = f2bf(sh.w + mx.w * dx.w);
    *(ushort4*)&Ak[off] = o;
    mx = *(const float4*)&mv[s];
    o.x = f2bf(sh.x + mx.x * dx.x); o.y = f2bf(sh.y + mx.y * dx.y);
    o.z = f2bf(sh.z + mx.z * dx.z); o.w = f2bf(sh.w + mx.w * dx.w);
    *(ushort4*)&Av[off] = o;
    mx = *(const float4*)&mr[s];
    o.x = f2bf(sh.x + mx.x * dx.x); o.y = f2bf(sh.y + mx.y * dx.y);
    o.z = f2bf(sh.z + mx.z * dx.z); o.w = f2bf(sh.w + mx.w * dx.w);
    *(ushort4*)&Ar[off] = o;
}

// ---------------- single-projection mix (fallback path) ----------------
__global__ __launch_bounds__(256)
void mix_kernel(const float* __restrict__ x, const float* __restrict__ mix,
                ushort* __restrict__ outA)
{
    const int idx = blockIdx.x * 256 + threadIdx.x;
    const int m = idx >> 8;
    const int s = (idx & 255) << 2;
    const float4 xv = *(const float4*)&x[(size_t)m * SD + s];
    float4 sh = make_float4(0.f, 0.f, 0.f, 0.f);
    if (m & (U_DIM - 1)) sh = *(const float4*)&x[(size_t)(m - 1) * SD + s];
    const float4 mx = *(const float4*)&mix[s];
    ushort4 o;
    o.x = f2bf(sh.x + mx.x * (xv.x - sh.x));
    o.y = f2bf(sh.y + mx.y * (xv.y - sh.y));
    o.z = f2bf(sh.z + mx.z * (xv.z - sh.z));
    o.w = f2bf(sh.w + mx.w * (xv.w - sh.w));
    *(ushort4*)&outA[(size_t)m * SD + s] = o;
}

// ============ 256x256 8-phase bf16 MFMA GEMM (m201-style, plain HIP) ============
// C[M,N] = A[M,K] @ (BT[N,K])^T + bias     M=8192, N=1024, K=1024
// FUSED==3: grid.z selects {k,v,r}: A/BT/bias/out per z, sigmoid at z==2, bf16 out
// FUSED==0: bf16 out   FUSED==1: bf16+sigmoid   FUSED==2: f32 out
// 512 threads = 8 waves (2M x 4N); wave tile 128x64 scattered as 4 quadrants 64x32,
// quadrant (qm,qn) lives at rows qm*128+(wv>>2)*64, cols qn*128+(wv&3)*32.
// Phase p of a K-tile computes quadrant (p>>1, p&1) over K=64 -> 16 MFMA, 12 ds_read_b128.
// LDS [2buf][2half][2kplane][128 rows][32 cols] per operand; rows 64B;
// swizzle: 16B chunk q stored from source chunk q^((row>>1)&3) (round-3-proven, 0 conflicts).
// Staging: 1 half-tile (2 global_load_lds) per phase; vmcnt(4)+barrier at phases 4/8 only.
template<int FUSED>
__global__ __launch_bounds__(512)
void gemm256(const ushort* __restrict__ Abase, const ushort* __restrict__ WTbase,
             const float* __restrict__ b0, const float* __restrict__ b1,
             const float* __restrict__ b2, void* __restrict__ Cbase)
{
    __shared__ ushort LA[2][2][2][128][32];   // 64 KB
    __shared__ ushort LB[2][2][2][128][32];   // 64 KB

    const int tid = threadIdx.x;
    const int wv  = tid >> 6, ln = tid & 63;

    // XCD-bijective block swizzle (nwg % 8 == 0 for all our grids)
    const int nwg = (int)(gridDim.x * gridDim.y * gridDim.z);
    int bid = (int)blockIdx.x + 32 * ((int)blockIdx.y + 4 * (int)blockIdx.z);
    const int cpx = nwg >> 3;
    const int s_  = (bid & 7) * cpx + (bid >> 3);
    const int mb  = s_ & 31;          // M fastest: consecutive per-XCD blocks share W panel
    const int nbz = s_ >> 5;
    const int nb  = nbz & 3;
    const int z   = nbz >> 2;
    const int m0 = mb * 256, n0 = nb * 256;

    const ushort* A; const ushort* BT; const float* bias; void* Cout; int dosig;
    if (FUSED == 3) {
        A    = Abase + (size_t)z * ((size_t)M_DIM * SD);
        BT   = WTbase + (size_t)z * ((size_t)SD * SD);
        bias = (z == 0) ? b0 : (z == 1) ? b1 : b2;
        Cout = (void*)((ushort*)Cbase + (size_t)z * ((size_t)M_DIM * SD));
        dosig = (z == 2);
    } else {
        A = Abase; BT = WTbase; bias = b0; Cout = Cbase; dosig = (FUSED == 1);
    }

    // ---- staging maps (per-lane global source, inverse-swizzled; linear LDS dest) ----
    const int srow = tid >> 2;                                  // 0..127
    const int ssw  = (((tid & 3) ^ ((tid >> 3) & 3)) << 3);     // element offset in row
    const size_t aS0 = (size_t)(m0 + srow) * SD + ssw;
    const size_t aS1 = (size_t)(m0 + 128 + srow) * SD + ssw;
    const size_t bS0 = (size_t)(n0 + srow) * SD + ssw;
    const size_t bS1 = (size_t)(n0 + 128 + srow) * SD + ssw;
    char* const laW = (char*)LA + wv * 1024;    // wave-uniform LDS bases
    char* const lbW = (char*)LB + wv * 1024;

    // ---- fragment-read maps (swizzled) ----
    const char* LAc = (const char*)LA;
    const char* LBc = (const char*)LB;
    const int lr  = ln & 15;
    const int kof = (((ln >> 4) ^ ((lr >> 1) & 3)) << 4);       // byte offset of 16B chunk
    const int aRd = ((wv >> 2) << 12) + lr * 64 + kof;          // + mt*1024 + kh*8192 ...
    const int bRd = ((wv & 3) << 11) + lr * 64 + kof;           // + nt*1024 + kh*8192 ...

    f32x4 acc[8][4];
    #pragma unroll
    for (int i = 0; i < 8; ++i)
        #pragma unroll
        for (int j = 0; j < 4; ++j)
            acc[i][j] = (f32x4){0.f, 0.f, 0.f, 0.f};

#define STG_A(buf, half, kt)                                                        \
    do { const size_t s0 = ((half) ? aS1 : aS0) + (size_t)(kt) * 64;                \
        __builtin_amdgcn_global_load_lds((glb_t*)(A + s0),                          \
            (lds_t*)(laW + (buf) * 32768 + (half) * 16384), 16, 0, 0);              \
        __builtin_amdgcn_global_load_lds((glb_t*)(A + s0 + 32),                     \
            (lds_t*)(laW + (buf) * 32768 + (half) * 16384 + 8192), 16, 0, 0);       \
    } while (0)

#define STG_B(buf, half, kt)                                                        \
    do { const size_t s0 = ((half) ? bS1 : bS0) + (size_t)(kt) * 64;                \
        __builtin_amdgcn_global_load_lds((glb_t*)(BT + s0),                         \
            (lds_t*)(lbW + (buf) * 32768 + (half) * 16384), 16, 0, 0);              \
        __builtin_amdgcn_global_load_lds((glb_t*)(BT + s0 + 32),                    \
            (lds_t*)(lbW + (buf) * 32768 + (half) * 16384 + 8192), 16, 0, 0);       \
    } while (0)

#define PHASE(buf, qm, qn, STG, DOVM)                                               \
    do {                                                                            \
        short8 af[4][2], bq[2][2];                                                  \
        _Pragma("unroll")                                                           \
        for (int mt = 0; mt < 4; ++mt) {                                            \
            af[mt][0] = *(const short8*)(LAc + (buf) * 32768 + (qm) * 16384         \
                                         + mt * 1024 + aRd);                        \
            af[mt][1] = *(const short8*)(LAc + (buf) * 32768 + (qm) * 16384         \
                                         + 8192 + mt * 1024 + aRd);                 \
        }                                                                           \
        _Pragma("unroll")                                                           \
        for (int nt = 0; nt < 2; ++nt) {                                            \
            bq[nt][0] = *(const short8*)(LBc + (buf) * 32768 + (qn) * 16384         \
                                         + nt * 1024 + bRd);                        \
            bq[nt][1] = *(const short8*)(LBc + (buf) * 32768 + (qn) * 16384         \
                                         + 8192 + nt * 1024 + bRd);                 \
        }                                                                           \
        STG;                                                                        \
        __builtin_amdgcn_s_barrier();                                               \
        __builtin_amdgcn_s_setprio(1);                                              \
        _Pragma("unroll")                                                           \
        for (int mt = 0; mt < 4; ++mt)                                              \
            _Pragma("unroll")                                                       \
            for (int nt = 0; nt < 2; ++nt) {                                        \
                acc[(qm) * 4 + mt][(qn) * 2 + nt] =                                 \
                    __builtin_amdgcn_mfma_f32_16x16x32_bf16(af[mt][0], bq[nt][0],   \
                        acc[(qm) * 4 + mt][(qn) * 2 + nt], 0, 0, 0);                \
                acc[(qm) * 4 + mt][(qn) * 2 + nt] =                                 \
                    __builtin_amdgcn_mfma_f32_16x16x32_bf16(af[mt][1], bq[nt][1],   \
                        acc[(qm) * 4 + mt][(qn) * 2 + nt], 0, 0, 0);                \
            }                                                                       \
        __builtin_amdgcn_s_setprio(0);                                              \
        if (DOVM) { asm volatile("s_waitcnt vmcnt(4)" ::: "memory"); }              \
        __builtin_amdgcn_s_barrier();                                               \
    } while (0)

    // ---- prologue: tile0 (buf0) fully + A0/B0 of tile1 (buf1) ----
    STG_A(0, 0, 0); STG_B(0, 0, 0);          // A0(0), B0(0)
    STG_A(0, 1, 0); STG_B(0, 1, 0);          // A1(0), B1(0)
    STG_A(1, 0, 1); STG_B(1, 0, 1);          // A0(1), B0(1)
    asm volatile("s_waitcnt vmcnt(4)" ::: "memory");   // tile0 complete; 2 halves in flight
    __builtin_amdgcn_s_barrier();

    // ---- main loop: 8 iters x 8 phases, 2 K-tiles per iter (16 K-tiles) ----
    for (int i = 0; i < 8; ++i) {
        const int t  = 2 * i;
        const int t2 = (t + 2 < 16) ? t + 2 : 15;   // clamp: harmless re-stage at tail
        const int t3 = (t + 3 < 16) ? t + 3 : 15;
        PHASE(0, 0, 0, STG_A(1, 1, t + 1), 0);   // stage A1(t+1) -> buf1
        PHASE(0, 0, 1, STG_B(1, 1, t + 1), 0);   // stage B1(t+1) -> buf1
        PHASE(0, 1, 0, STG_A(0, 0, t2), 0);      // stage A0(t+2) -> buf0
        PHASE(0, 1, 1, STG_B(0, 0, t2), 1);      // stage B0(t+2); vmcnt(4): tile t+1 ready
        PHASE(1, 0, 0, STG_A(0, 1, t2), 0);      // stage A1(t+2) -> buf0
        PHASE(1, 0, 1, STG_B(0, 1, t2), 0);      // stage B1(t+2) -> buf0
        PHASE(1, 1, 0, STG_A(1, 0, t3), 0);      // stage A0(t+3) -> buf1
        PHASE(1, 1, 1, STG_B(1, 0, t3), 1);      // stage B0(t+3); vmcnt(4): tile t+2 ready
    }

#undef PHASE
#undef STG_A
#undef STG_B

    // ---- epilogue: frag row = (ln>>4)*4 + j, col = ln&15 (m89-verified) ----
    const int cr = (ln >> 4) * 4;
    const int cc = ln & 15;
    const int wm = (wv >> 2) * 64;
    const int wn = (wv & 3) * 32;
    #pragma unroll
    for (int qm = 0; qm < 2; ++qm)
    #pragma unroll
    for (int qn = 0; qn < 2; ++qn)
    #pragma unroll
    for (int mt = 0; mt < 4; ++mt)
    #pragma unroll
    for (int nt = 0; nt < 2; ++nt) {
        const int gc = n0 + qn * 128 + wn + nt * 16 + cc;
        const float bv = bias[gc];
        #pragma unroll
        for (int j = 0; j < 4; ++j) {
            const int gr = m0 + qm * 128 + wm + mt * 16 + cr + j;
            float v = acc[qm * 4 + mt][qn * 2 + nt][j] + bv;
            if (FUSED == 1 || FUSED == 3) { if (dosig) v = 1.f / (1.f + __expf(-v)); }
            if (FUSED == 2)
                ((float*)Cout)[(size_t)gr * SD + gc] = v;
            else
                ((ushort*)Cout)[(size_t)gr * SD + gc] = f2bf(v);
        }
    }
}

// ---------------- scan pass 1: per-chunk local states from zero init ----------------
__global__ __launch_bounds__(256)
void scan_local(const ushort* __restrict__ kq, const ushort* __restrict__ vq,
                const float* __restrict__ td,
                float* __restrict__ sa, float* __restrict__ sb, float* __restrict__ sp)
{
    const int idx = blockIdx.x * 256 + threadIdx.x;   // 8192*NC
    const int ch = idx & (M_DIM - 1);
    const int c  = idx >> 13;
    const int b  = ch >> 10, d = ch & (SD - 1);
    const float w = -__expf(td[d]);
    size_t ptr = (size_t)b * U_DIM * SD + (size_t)(c * CT) * SD + d;

    float a = 0.f, bb = 0.f, p = -1e38f;
    for (int s = 0; s < CT; ++s) {
        const float kt = bf2f(kq[ptr]), vt = bf2f(vq[ptr]);
        const float q2 = fmaxf(p + w, kt);
        const float e1 = __expf(p + w - q2);
        const float e2 = __expf(kt - q2);
        a = e1 * a + e2 * vt; bb = e1 * bb + e2; p = q2;
        ptr += SD;
    }
    sa[idx] = a; sb[idx] = bb; sp[idx] = p;
}

// ---------------- scan pass 2: sequential prefix-combine over chunks ----------------
__global__ __launch_bounds__(256)
void scan_prefix(const float* __restrict__ td,
                 float* __restrict__ sa, float* __restrict__ sb, float* __restrict__ sp)
{
    const int ch = blockIdx.x * 256 + threadIdx.x;    // 8192
    const float wT = -__expf(td[ch & (SD - 1)]) * (float)CT;
    float ca = 0.f, cb = 0.f, cp = -1e38f;
    for (int c = 0; c < NC; ++c) {
        const int i = c * M_DIM + ch;
        const float la = sa[i], lb = sb[i], lp = sp[i];
        sa[i] = ca; sb[i] = cb; sp[i] = cp;
        const float pd = cp + wT;                      // decay carry across chunk
        const float q  = fmaxf(pd, lp);
        const float e1 = __expf(pd - q);
        const float e2 = __expf(lp - q);
        ca = e1 * ca + e2 * la; cb = e1 * cb + e2 * lb; cp = q;
    }
}

// ---------------- scan pass 3: outputs r*wkv (bf16) from incoming states ----------------
__global__ __launch_bounds__(256)
void scan_out(const ushort* __restrict__ kq, const ushort* __restrict__ vq,
              const ushort* __restrict__ rq,
              const float* __restrict__ td, const float* __restrict__ tfirst,
              const float* __restrict__ sa, const float* __restrict__ sb,
              const float* __restrict__ sp,
              ushort* __restrict__ rw)
{
    const int idx = blockIdx.x * 256 + threadIdx.x;
    const int ch = idx & (M_DIM - 1);
    const int c  = idx >> 13;
    const int b  = ch >> 10, d = ch & (SD - 1);
    const float w  = -__expf(td[d]);
    const float tf = tfirst[d];
    size_t ptr = (size_t)b * U_DIM * SD + (size_t)(c * CT) * SD + d;

    float a = sa[idx], bb = sb[idx], p = sp[idx];
    for (int s = 0; s < CT; ++s) {
        const float kt = bf2f(kq[ptr]), vt = bf2f(vq[ptr]), rt = bf2f(rq[ptr]);
        const float q  = fmaxf(p, tf + kt);
        const float e1 = __expf(p - q);
        const float e2 = __expf(tf + kt - q);
        const float ov = (e1 * a + e2 * vt) * __builtin_amdgcn_rcpf(e1 * bb + e2);
        const float q2  = fmaxf(p + w, kt);
        const float e1b = __expf(p + w - q2);
        const float e2b = __expf(kt - q2);
        a = e1b * a + e2b * vt; bb = e1b * bb + e2b; p = q2;
        rw[ptr] = f2bf(rt * ov);
        ptr += SD;
    }
}

extern "C" void kernel_launch(void* const* d_in, const int* in_sizes, int n_in,
                              void* d_out, int out_size, void* d_ws, size_t ws_size,
                              hipStream_t stream)
{
    (void)in_sizes; (void)n_in; (void)out_size;
    const float* x  = (const float*)d_in[0];
    const float* td = (const float*)d_in[1];
    const float* tf = (const float*)d_in[2];
    const float* mk = (const float*)d_in[3];
    const float* mv = (const float*)d_in[4];
    const float* mr = (const float*)d_in[5];
    const float* Wk = (const float*)d_in[6];
    const float* bk = (const float*)d_in[7];
    const float* Wv = (const float*)d_in[8];
    const float* bv = (const float*)d_in[9];
    const float* Wr = (const float*)d_in[10];
    const float* br = (const float*)d_in[11];
    const float* Wo = (const float*)d_in[12];
    const float* bo = (const float*)d_in[13];
    float* out = (float*)d_out;

    const size_t NE = (size_t)M_DIM * SD;   // 8M elements
    const size_t WS = (size_t)SD * SD;
    char* ws = (char*)d_ws;

    const dim3 gg1(32, 4, 1);
    const dim3 gg3(32, 4, 3);

    if (ws_size >= ((size_t)108 << 20)) {
        // fused layout: WT 0-8 | Ak 8-24 | Av 24-40 | Ar 40-56 | k 56-72 | v 72-88 |
        //               r 88-104 | states 104-107  (MB)
        ushort* WT  = (ushort*)ws;
        ushort* Ak  = (ushort*)(ws + ((size_t)8   << 20));
        ushort* kvr = (ushort*)(ws + ((size_t)56  << 20));
        float*  sa  = (float*)(ws + ((size_t)104 << 20));
        float*  sb  = (float*)(ws + ((size_t)105 << 20));
        float*  sp  = (float*)(ws + ((size_t)106 << 20));
        ushort* kbuf = kvr;
        ushort* vbuf = kvr + NE;
        ushort* rbuf = kvr + 2 * NE;
        ushort* rwkv = Ak;                  // A-buffers dead after proj GEMM

        wtrans_kernel<<<dim3(32, 32, 4), 256, 0, stream>>>(Wk, Wv, Wr, Wo, WT);
        mix3_kernel<<<8192, 256, 0, stream>>>(x, mk, mv, mr, Ak, Ak + NE, Ak + 2 * NE);
        gemm256<3><<<gg3, 512, 0, stream>>>(Ak, WT, bk, bv, br, kvr);

        scan_local <<<(M_DIM * NC) / 256, 256, 0, stream>>>(kbuf, vbuf, td, sa, sb, sp);
        scan_prefix<<<M_DIM / 256, 256, 0, stream>>>(td, sa, sb, sp);
        scan_out   <<<(M_DIM * NC) / 256, 256, 0, stream>>>(kbuf, vbuf, rbuf, td, tf,
                                                            sa, sb, sp, rwkv);

        gemm256<2><<<gg1, 512, 0, stream>>>(rwkv, WT + 3 * WS, bo, bo, bo, out);
    } else {
        // sequential layout (75 MB)
        ushort* WT   = (ushort*)ws;
        ushort* Abuf = (ushort*)(ws + ((size_t)8  << 20));
        ushort* kbuf = (ushort*)(ws + ((size_t)24 << 20));
        ushort* vbuf = (ushort*)(ws + ((size_t)40 << 20));
        ushort* rbuf = (ushort*)(ws + ((size_t)56 << 20));
        float*  sa   = (float*)(ws + ((size_t)72 << 20));
        float*  sb   = (float*)(ws + ((size_t)73 << 20));
        float*  sp   = (float*)(ws + ((size_t)74 << 20));
        ushort* rwkv = Abuf;

        wtrans_kernel<<<dim3(32, 32, 4), 256, 0, stream>>>(Wk, Wv, Wr, Wo, WT);
        mix_kernel<<<8192, 256, 0, stream>>>(x, mk, Abuf);
        gemm256<0><<<gg1, 512, 0, stream>>>(Abuf, WT, bk, bk, bk, kbuf);
        mix_kernel<<<8192, 256, 0, stream>>>(x, mv, Abuf);
        gemm256<0><<<gg1, 512, 0, stream>>>(Abuf, WT + WS, bv, bv, bv, vbuf);
        mix_kernel<<<8192, 256, 0, stream>>>(x, mr, Abuf);
        gemm256<1><<<gg1, 512, 0, stream>>>(Abuf, WT + 2 * WS, br, br, br, rbuf);

        scan_local <<<(M_DIM * NC) / 256, 256, 0, stream>>>(kbuf, vbuf, td, sa, sb, sp);
        scan_prefix<<<M_DIM / 256, 256, 0, stream>>>(td, sa, sb, sp);
        scan_out   <<<(M_DIM * NC) / 256, 256, 0, stream>>>(kbuf, vbuf, rbuf, td, tf,
                                                            sa, sb, sp, rwkv);

        gemm256<2><<<gg1, 512, 0, stream>>>(rwkv, WT + 3 * WS, bo, bo, bo, out);
    }
}

// Round 5
// 176.859 us; speedup vs baseline: 1.0488x; 1.0488x over previous
//
#include <hip/hip_runtime.h>
#include <cstdint>
#include <cstddef>

#define B_DIM 8
#define U_DIM 1024
#define SD    1024                 // SIZE == D_ATT == 1024
#define M_DIM (B_DIM * U_DIM)      // 8192 rows; also B*D channel count
#define NC 32                      // scan chunks
#define CT 32                      // tokens per chunk (NC*CT == U_DIM)

typedef __attribute__((ext_vector_type(8))) short short8;
typedef __attribute__((ext_vector_type(4))) float f32x4;

typedef __attribute__((address_space(3))) void       lds_t;
typedef const __attribute__((address_space(1))) void glb_t;

__device__ __forceinline__ ushort f2bf(float f) {
    union { float f; uint32_t u; } c; c.f = f;
    uint32_t r = (c.u + 0x7FFFu + ((c.u >> 16) & 1u)) >> 16;   // RNE
    return (ushort)r;
}
__device__ __forceinline__ float bf2f(ushort h) {
    union { float f; uint32_t u; } c; c.u = ((uint32_t)h) << 16; return c.f;
}

// ---------------- prepass: W[K][N] f32 -> W^T[N][K] bf16, 4 matrices ----------------
__global__ __launch_bounds__(256)
void wtrans_kernel(const float* __restrict__ Wk, const float* __restrict__ Wv,
                   const float* __restrict__ Wr, const float* __restrict__ Wo,
                   ushort* __restrict__ WT)
{
    __shared__ float t[32][33];
    const float* W = (blockIdx.z == 0) ? Wk : (blockIdx.z == 1) ? Wv
                   : (blockIdx.z == 2) ? Wr : Wo;
    ushort* o = WT + (size_t)blockIdx.z * SD * SD;
    const int tx = threadIdx.x & 31, ty = threadIdx.x >> 5;
    const int k0 = blockIdx.y * 32, n0 = blockIdx.x * 32;
    #pragma unroll
    for (int i = 0; i < 4; ++i)
        t[ty + i * 8][tx] = W[(size_t)(k0 + ty + i * 8) * SD + n0 + tx];
    __syncthreads();
    #pragma unroll
    for (int i = 0; i < 4; ++i)
        o[(size_t)(n0 + ty + i * 8) * SD + k0 + tx] = f2bf(t[tx][ty + i * 8]);
}

// ---------------- prepass: A_j = sh + mix_j*(x - sh), bf16, all three in one pass ----
__global__ __launch_bounds__(256)
void mix3_kernel(const float* __restrict__ x,
                 const float* __restrict__ mk, const float* __restrict__ mv,
                 const float* __restrict__ mr,
                 ushort* __restrict__ Ak, ushort* __restrict__ Av,
                 ushort* __restrict__ Ar)
{
    const int idx = blockIdx.x * 256 + threadIdx.x;  // 2M groups of 4
    const int m = idx >> 8;
    const int s = (idx & 255) << 2;
    const float4 xv = *(const float4*)&x[(size_t)m * SD + s];
    float4 sh = make_float4(0.f, 0.f, 0.f, 0.f);
    if (m & (U_DIM - 1)) sh = *(const float4*)&x[(size_t)(m - 1) * SD + s];
    const float4 dx = make_float4(xv.x - sh.x, xv.y - sh.y, xv.z - sh.z, xv.w - sh.w);
    const size_t off = (size_t)m * SD + s;

    float4 mx;
    ushort4 o;
    mx = *(const float4*)&mk[s];
    o.x = f2bf(sh.x + mx.x * dx.x); o.y = f2bf(sh.y + mx.y * dx.y);
    o.z = f2bf(sh.z + mx.z * dx.z); o.w = f2bf(sh.w + mx.w * dx.w);
    *(ushort4*)&Ak[off] = o;
    mx = *(const float4*)&mv[s];
    o.x = f2bf(sh.x + mx.x * dx.x); o.y = f2bf(sh.y + mx.y * dx.y);
    o.z = f2bf(sh.z + mx.z * dx.z); o.w = f2bf(sh.w + mx.w * dx.w);
    *(ushort4*)&Av[off] = o;
    mx = *(const float4*)&mr[s];
    o.x = f2bf(sh.x + mx.x * dx.x); o.y = f2bf(sh.y + mx.y * dx.y);
    o.z = f2bf(sh.z + mx.z * dx.z); o.w = f2bf(sh.w + mx.w * dx.w);
    *(ushort4*)&Ar[off] = o;
}

// ---------------- single-projection mix (fallback path) ----------------
__global__ __launch_bounds__(256)
void mix_kernel(const float* __restrict__ x, const float* __restrict__ mix,
                ushort* __restrict__ outA)
{
    const int idx = blockIdx.x * 256 + threadIdx.x;
    const int m = idx >> 8;
    const int s = (idx & 255) << 2;
    const float4 xv = *(const float4*)&x[(size_t)m * SD + s];
    float4 sh = make_float4(0.f, 0.f, 0.f, 0.f);
    if (m & (U_DIM - 1)) sh = *(const float4*)&x[(size_t)(m - 1) * SD + s];
    const float4 mx = *(const float4*)&mix[s];
    ushort4 o;
    o.x = f2bf(sh.x + mx.x * (xv.x - sh.x));
    o.y = f2bf(sh.y + mx.y * (xv.y - sh.y));
    o.z = f2bf(sh.z + mx.z * (xv.z - sh.z));
    o.w = f2bf(sh.w + mx.w * (xv.w - sh.w));
    *(ushort4*)&outA[(size_t)m * SD + s] = o;
}

// ======== 256x128 bf16 MFMA GEMM, 2-phase-per-K-tile, 3-deep pipeline ========
// C[M,N] = A[M,K] @ (BT[N,K])^T + bias   M=8192, N=1024, K=1024
// FUSED==3: grid (32,8,3), z selects {k,v,r}; sigmoid at z==2; bf16 out
// FUSED==0: bf16 out  FUSED==1: bf16+sigmoid  FUSED==2: f32 out  (grid (32,8,1))
// 512 threads = 8 waves as 4M x 2N; wave tile 64x64 (4x4 16x16 frags, held in regs).
// K-tile 64 split in 2 k-planes of 32; phase = {8 ds_read_b128 + 3 global_load_lds +
// barrier + 16 MFMA + vmcnt(9) + barrier}. 3 LDS buffers (144 KB): stage tile t+2
// during tile t -> 4-phase issue-to-drain distance; never vmcnt(0) in the loop.
// LDS row = 64B, 16B chunk q stored from source chunk q^((row>>1)&3) (0-conflict, r3/r4).
template<int FUSED>
__global__ __launch_bounds__(512)
void gemm_big(const ushort* __restrict__ Abase, const ushort* __restrict__ WTbase,
              const float* __restrict__ b0, const float* __restrict__ b1,
              const float* __restrict__ b2, void* __restrict__ Cbase)
{
    __shared__ ushort LA[3][2][256][32];   // 96 KB : [buf][kplane][row][32]
    __shared__ ushort LB[3][2][128][32];   // 48 KB

    const int tid = threadIdx.x;
    const int wv = tid >> 6, ln = tid & 63;
    const int wr = wv >> 1, wc = wv & 1;

    // bijective XCD swizzle (nwg: 768 or 256, both %8==0); mb fastest per XCD chunk
    const int nwg = (int)(gridDim.x * gridDim.y * gridDim.z);
    const int bid = (int)blockIdx.x +
                    (int)gridDim.x * ((int)blockIdx.y + (int)gridDim.y * (int)blockIdx.z);
    const int s_  = (bid & 7) * (nwg >> 3) + (bid >> 3);
    const int mb  = s_ & 31;
    const int nb  = (s_ >> 5) & 7;
    const int z   = s_ >> 8;
    const int m0 = mb * 256, n0 = nb * 128;

    const ushort* A; const ushort* BT; const float* bias; void* Cout; int dosig;
    if (FUSED == 3) {
        A    = Abase + (size_t)z * ((size_t)M_DIM * SD);
        BT   = WTbase + (size_t)z * ((size_t)SD * SD);
        bias = (z == 0) ? b0 : (z == 1) ? b1 : b2;
        Cout = (void*)((ushort*)Cbase + (size_t)z * ((size_t)M_DIM * SD));
        dosig = (z == 2);
    } else {
        A = Abase; BT = WTbase; bias = b0; Cout = Cbase; dosig = (FUSED == 1);
    }

    // ---- staging maps (linear LDS dest = tid*16B; inverse-swizzled global source) ----
    const int srow = tid >> 2;                                  // 0..127
    const int ssw  = ((tid & 3) ^ ((srow >> 1) & 3)) << 3;      // element offset in row
    const ushort* aSrc0 = A  + (size_t)(m0 + srow) * SD + ssw;
    const ushort* aSrc1 = aSrc0 + (size_t)128 * SD;
    const ushort* bSrc  = BT + (size_t)(n0 + srow) * SD + ssw;
    char* const laW = (char*)LA + wv * 1024;    // wave-uniform LDS bases
    char* const lbW = (char*)LB + wv * 1024;

    // ---- fragment-read maps (swizzled) ----
    const char* LAc = (const char*)LA;
    const char* LBc = (const char*)LB;
    const int lr  = ln & 15;
    const int lq  = ln >> 4;
    const int kof = ((lq ^ ((lr >> 1) & 3)) << 4);
    const int aRd = wr * 4096 + lr * 64 + kof;
    const int bRd = wc * 4096 + lr * 64 + kof;

    f32x4 acc[4][4];
    #pragma unroll
    for (int i = 0; i < 4; ++i)
        #pragma unroll
        for (int j = 0; j < 4; ++j)
            acc[i][j] = (f32x4){0.f, 0.f, 0.f, 0.f};

#define STG(bufS, ks, kt)                                                           \
    do { const int off = (kt) * 64 + (ks) * 32;                                     \
        __builtin_amdgcn_global_load_lds((glb_t*)(aSrc0 + off),                     \
            (lds_t*)(laW + (bufS) * 32768 + (ks) * 16384), 16, 0, 0);               \
        __builtin_amdgcn_global_load_lds((glb_t*)(aSrc1 + off),                     \
            (lds_t*)(laW + (bufS) * 32768 + (ks) * 16384 + 8192), 16, 0, 0);        \
        __builtin_amdgcn_global_load_lds((glb_t*)(bSrc + off),                      \
            (lds_t*)(lbW + (bufS) * 16384 + (ks) * 8192), 16, 0, 0);                \
    } while (0)

#define PHASE(bR, ks, bS, kt)                                                       \
    do {                                                                            \
        short8 af[4], bq[4];                                                        \
        _Pragma("unroll")                                                           \
        for (int mt = 0; mt < 4; ++mt)                                              \
            af[mt] = *(const short8*)(LAc + (bR) * 32768 + (ks) * 16384             \
                                      + mt * 1024 + aRd);                           \
        _Pragma("unroll")                                                           \
        for (int nt = 0; nt < 4; ++nt)                                              \
            bq[nt] = *(const short8*)(LBc + (bR) * 16384 + (ks) * 8192              \
                                      + nt * 1024 + bRd);                           \
        STG(bS, ks, kt);                                                            \
        __builtin_amdgcn_s_barrier();                                               \
        __builtin_amdgcn_s_setprio(1);                                              \
        _Pragma("unroll")                                                           \
        for (int mt = 0; mt < 4; ++mt)                                              \
            _Pragma("unroll")                                                       \
            for (int nt = 0; nt < 4; ++nt)                                          \
                acc[mt][nt] = __builtin_amdgcn_mfma_f32_16x16x32_bf16(              \
                    af[mt], bq[nt], acc[mt][nt], 0, 0, 0);                          \
        __builtin_amdgcn_s_setprio(0);                                              \
        asm volatile("s_waitcnt vmcnt(9)" ::: "memory");                            \
        __builtin_amdgcn_s_barrier();                                               \
    } while (0)

    // ---- prologue: stage tiles 0 and 1 fully (12 loads); wait for tile0 plane0 ----
    STG(0, 0, 0); STG(0, 1, 0);
    STG(1, 0, 1); STG(1, 1, 1);
    asm volatile("s_waitcnt vmcnt(9)" ::: "memory");
    __builtin_amdgcn_s_barrier();

    // ---- main loop: 16 K-tiles, 2 phases each; stage tile t+2 during tile t ----
    for (int t = 0; t < 16; ++t) {
        const int bR = t % 3;
        const int tn = (t + 2 < 16) ? t + 2 : 15;   // clamped tail re-stage: never read
        const int bS = (t + 2) % 3;
        PHASE(bR, 0, bS, tn);
        PHASE(bR, 1, bS, tn);
    }

#undef PHASE
#undef STG

    // ---- epilogue: frag row = lq*4 + j, col = lr (m89-verified) ----
    const int cr = lq * 4;
    const int cc = lr;
    #pragma unroll
    for (int mt = 0; mt < 4; ++mt)
    #pragma unroll
    for (int nt = 0; nt < 4; ++nt) {
        const int gc = n0 + wc * 64 + nt * 16 + cc;
        const float bv = bias[gc];
        #pragma unroll
        for (int j = 0; j < 4; ++j) {
            const int gr = m0 + wr * 64 + mt * 16 + cr + j;
            float v = acc[mt][nt][j] + bv;
            if (FUSED == 1 || FUSED == 3) { if (dosig) v = 1.f / (1.f + __expf(-v)); }
            if (FUSED == 2)
                ((float*)Cout)[(size_t)gr * SD + gc] = v;
            else
                ((ushort*)Cout)[(size_t)gr * SD + gc] = f2bf(v);
        }
    }
}

// ---------------- scan pass 1: per-chunk local states from zero init ----------------
__global__ __launch_bounds__(256)
void scan_local(const ushort* __restrict__ kq, const ushort* __restrict__ vq,
                const float* __restrict__ td,
                float* __restrict__ sa, float* __restrict__ sb, float* __restrict__ sp)
{
    const int idx = blockIdx.x * 256 + threadIdx.x;   // 8192*NC
    const int ch = idx & (M_DIM - 1);
    const int c  = idx >> 13;
    const int b  = ch >> 10, d = ch & (SD - 1);
    const float w = -__expf(td[d]);
    size_t ptr = (size_t)b * U_DIM * SD + (size_t)(c * CT) * SD + d;

    float a = 0.f, bb = 0.f, p = -1e38f;
    for (int s = 0; s < CT; ++s) {
        const float kt = bf2f(kq[ptr]), vt = bf2f(vq[ptr]);
        const float q2 = fmaxf(p + w, kt);
        const float e1 = __expf(p + w - q2);
        const float e2 = __expf(kt - q2);
        a = e1 * a + e2 * vt; bb = e1 * bb + e2; p = q2;
        ptr += SD;
    }
    sa[idx] = a; sb[idx] = bb; sp[idx] = p;
}

// ---------------- scan pass 2: sequential prefix-combine over chunks ----------------
__global__ __launch_bounds__(256)
void scan_prefix(const float* __restrict__ td,
                 float* __restrict__ sa, float* __restrict__ sb, float* __restrict__ sp)
{
    const int ch = blockIdx.x * 256 + threadIdx.x;    // 8192
    const float wT = -__expf(td[ch & (SD - 1)]) * (float)CT;
    float ca = 0.f, cb = 0.f, cp = -1e38f;
    for (int c = 0; c < NC; ++c) {
        const int i = c * M_DIM + ch;
        const float la = sa[i], lb = sb[i], lp = sp[i];
        sa[i] = ca; sb[i] = cb; sp[i] = cp;
        const float pd = cp + wT;                      // decay carry across chunk
        const float q  = fmaxf(pd, lp);
        const float e1 = __expf(pd - q);
        const float e2 = __expf(lp - q);
        ca = e1 * ca + e2 * la; cb = e1 * cb + e2 * lb; cp = q;
    }
}

// ---------------- scan pass 3: outputs r*wkv (bf16) from incoming states ----------------
__global__ __launch_bounds__(256)
void scan_out(const ushort* __restrict__ kq, const ushort* __restrict__ vq,
              const ushort* __restrict__ rq,
              const float* __restrict__ td, const float* __restrict__ tfirst,
              const float* __restrict__ sa, const float* __restrict__ sb,
              const float* __restrict__ sp,
              ushort* __restrict__ rw)
{
    const int idx = blockIdx.x * 256 + threadIdx.x;
    const int ch = idx & (M_DIM - 1);
    const int c  = idx >> 13;
    const int b  = ch >> 10, d = ch & (SD - 1);
    const float w  = -__expf(td[d]);
    const float tf = tfirst[d];
    size_t ptr = (size_t)b * U_DIM * SD + (size_t)(c * CT) * SD + d;

    float a = sa[idx], bb = sb[idx], p = sp[idx];
    for (int s = 0; s < CT; ++s) {
        const float kt = bf2f(kq[ptr]), vt = bf2f(vq[ptr]), rt = bf2f(rq[ptr]);
        const float q  = fmaxf(p, tf + kt);
        const float e1 = __expf(p - q);
        const float e2 = __expf(tf + kt - q);
        const float ov = (e1 * a + e2 * vt) * __builtin_amdgcn_rcpf(e1 * bb + e2);
        const float q2  = fmaxf(p + w, kt);
        const float e1b = __expf(p + w - q2);
        const float e2b = __expf(kt - q2);
        a = e1b * a + e2b * vt; bb = e1b * bb + e2b; p = q2;
        rw[ptr] = f2bf(rt * ov);
        ptr += SD;
    }
}

extern "C" void kernel_launch(void* const* d_in, const int* in_sizes, int n_in,
                              void* d_out, int out_size, void* d_ws, size_t ws_size,
                              hipStream_t stream)
{
    (void)in_sizes; (void)n_in; (void)out_size;
    const float* x  = (const float*)d_in[0];
    const float* td = (const float*)d_in[1];
    const float* tf = (const float*)d_in[2];
    const float* mk = (const float*)d_in[3];
    const float* mv = (const float*)d_in[4];
    const float* mr = (const float*)d_in[5];
    const float* Wk = (const float*)d_in[6];
    const float* bk = (const float*)d_in[7];
    const float* Wv = (const float*)d_in[8];
    const float* bv = (const float*)d_in[9];
    const float* Wr = (const float*)d_in[10];
    const float* br = (const float*)d_in[11];
    const float* Wo = (const float*)d_in[12];
    const float* bo = (const float*)d_in[13];
    float* out = (float*)d_out;

    const size_t NE = (size_t)M_DIM * SD;   // 8M elements
    const size_t WS = (size_t)SD * SD;
    char* ws = (char*)d_ws;

    const dim3 gg1(32, 8, 1);
    const dim3 gg3(32, 8, 3);

    if (ws_size >= ((size_t)108 << 20)) {
        // fused layout: WT 0-8 | Ak 8-24 | Av 24-40 | Ar 40-56 | k 56-72 | v 72-88 |
        //               r 88-104 | states 104-107  (MB)
        ushort* WT  = (ushort*)ws;
        ushort* Ak  = (ushort*)(ws + ((size_t)8   << 20));
        ushort* kvr = (ushort*)(ws + ((size_t)56  << 20));
        float*  sa  = (float*)(ws + ((size_t)104 << 20));
        float*  sb  = (float*)(ws + ((size_t)105 << 20));
        float*  sp  = (float*)(ws + ((size_t)106 << 20));
        ushort* kbuf = kvr;
        ushort* vbuf = kvr + NE;
        ushort* rbuf = kvr + 2 * NE;
        ushort* rwkv = Ak;                  // A-buffers dead after proj GEMM

        wtrans_kernel<<<dim3(32, 32, 4), 256, 0, stream>>>(Wk, Wv, Wr, Wo, WT);
        mix3_kernel<<<8192, 256, 0, stream>>>(x, mk, mv, mr, Ak, Ak + NE, Ak + 2 * NE);
        gemm_big<3><<<gg3, 512, 0, stream>>>(Ak, WT, bk, bv, br, kvr);

        scan_local <<<(M_DIM * NC) / 256, 256, 0, stream>>>(kbuf, vbuf, td, sa, sb, sp);
        scan_prefix<<<M_DIM / 256, 256, 0, stream>>>(td, sa, sb, sp);
        scan_out   <<<(M_DIM * NC) / 256, 256, 0, stream>>>(kbuf, vbuf, rbuf, td, tf,
                                                            sa, sb, sp, rwkv);

        gemm_big<2><<<gg1, 512, 0, stream>>>(rwkv, WT + 3 * WS, bo, bo, bo, out);
    } else {
        // sequential layout (75 MB)
        ushort* WT   = (ushort*)ws;
        ushort* Abuf = (ushort*)(ws + ((size_t)8  << 20));
        ushort* kbuf = (ushort*)(ws + ((size_t)24 << 20));
        ushort* vbuf = (ushort*)(ws + ((size_t)40 << 20));
        ushort* rbuf = (ushort*)(ws + ((size_t)56 << 20));
        float*  sa   = (float*)(ws + ((size_t)72 << 20));
        float*  sb   = (float*)(ws + ((size_t)73 << 20));
        float*  sp   = (float*)(ws + ((size_t)74 << 20));
        ushort* rwkv = Abuf;

        wtrans_kernel<<<dim3(32, 32, 4), 256, 0, stream>>>(Wk, Wv, Wr, Wo, WT);
        mix_kernel<<<8192, 256, 0, stream>>>(x, mk, Abuf);
        gemm_big<0><<<gg1, 512, 0, stream>>>(Abuf, WT, bk, bk, bk, kbuf);
        mix_kernel<<<8192, 256, 0, stream>>>(x, mv, Abuf);
        gemm_big<0><<<gg1, 512, 0, stream>>>(Abuf, WT + WS, bv, bv, bv, vbuf);
        mix_kernel<<<8192, 256, 0, stream>>>(x, mr, Abuf);
        gemm_big<1><<<gg1, 512, 0, stream>>>(Abuf, WT + 2 * WS, br, br, br, rbuf);

        scan_local <<<(M_DIM * NC) / 256, 256, 0, stream>>>(kbuf, vbuf, td, sa, sb, sp);
        scan_prefix<<<M_DIM / 256, 256, 0, stream>>>(td, sa, sb, sp);
        scan_out   <<<(M_DIM * NC) / 256, 256, 0, stream>>>(kbuf, vbuf, rbuf, td, tf,
                                                            sa, sb, sp, rwkv);

        gemm_big<2><<<gg1, 512, 0, stream>>>(rwkv, WT + 3 * WS, bo, bo, bo, out);
    }
}

// Round 6
// 168.726 us; speedup vs baseline: 1.0993x; 1.0482x over previous
//
#include <hip/hip_runtime.h>
#include <cstdint>
#include <cstddef>

#define B_DIM 8
#define U_DIM 1024
#define SD    1024                 // SIZE == D_ATT == 1024
#define M_DIM (B_DIM * U_DIM)      // 8192 rows; also B*D channel count
#define NC 32                      // scan chunks
#define CT 32                      // tokens per chunk (NC*CT == U_DIM)

typedef __attribute__((ext_vector_type(8))) short short8;
typedef __attribute__((ext_vector_type(4))) float f32x4;

typedef __attribute__((address_space(3))) void       lds_t;
typedef const __attribute__((address_space(1))) void glb_t;

__device__ __forceinline__ ushort f2bf(float f) {
    union { float f; uint32_t u; } c; c.f = f;
    uint32_t r = (c.u + 0x7FFFu + ((c.u >> 16) & 1u)) >> 16;   // RNE
    return (ushort)r;
}
__device__ __forceinline__ float bf2f(ushort h) {
    union { float f; uint32_t u; } c; c.u = ((uint32_t)h) << 16; return c.f;
}

// ---------------- prepass: W[K][N] f32 -> W^T[N][K] bf16, 4 matrices ----------------
__global__ __launch_bounds__(256)
void wtrans_kernel(const float* __restrict__ Wk, const float* __restrict__ Wv,
                   const float* __restrict__ Wr, const float* __restrict__ Wo,
                   ushort* __restrict__ WT)
{
    __shared__ float t[32][33];
    const float* W = (blockIdx.z == 0) ? Wk : (blockIdx.z == 1) ? Wv
                   : (blockIdx.z == 2) ? Wr : Wo;
    ushort* o = WT + (size_t)blockIdx.z * SD * SD;
    const int tx = threadIdx.x & 31, ty = threadIdx.x >> 5;
    const int k0 = blockIdx.y * 32, n0 = blockIdx.x * 32;
    #pragma unroll
    for (int i = 0; i < 4; ++i)
        t[ty + i * 8][tx] = W[(size_t)(k0 + ty + i * 8) * SD + n0 + tx];
    __syncthreads();
    #pragma unroll
    for (int i = 0; i < 4; ++i)
        o[(size_t)(n0 + ty + i * 8) * SD + k0 + tx] = f2bf(t[tx][ty + i * 8]);
}

// ---------------- prepass: A_j = sh + mix_j*(x - sh), bf16, all three in one pass ----
__global__ __launch_bounds__(256)
void mix3_kernel(const float* __restrict__ x,
                 const float* __restrict__ mk, const float* __restrict__ mv,
                 const float* __restrict__ mr,
                 ushort* __restrict__ Ak, ushort* __restrict__ Av,
                 ushort* __restrict__ Ar)
{
    const int idx = blockIdx.x * 256 + threadIdx.x;  // 2M groups of 4
    const int m = idx >> 8;
    const int s = (idx & 255) << 2;
    const float4 xv = *(const float4*)&x[(size_t)m * SD + s];
    float4 sh = make_float4(0.f, 0.f, 0.f, 0.f);
    if (m & (U_DIM - 1)) sh = *(const float4*)&x[(size_t)(m - 1) * SD + s];
    const float4 dx = make_float4(xv.x - sh.x, xv.y - sh.y, xv.z - sh.z, xv.w - sh.w);
    const size_t off = (size_t)m * SD + s;

    float4 mx;
    ushort4 o;
    mx = *(const float4*)&mk[s];
    o.x = f2bf(sh.x + mx.x * dx.x); o.y = f2bf(sh.y + mx.y * dx.y);
    o.z = f2bf(sh.z + mx.z * dx.z); o.w = f2bf(sh.w + mx.w * dx.w);
    *(ushort4*)&Ak[off] = o;
    mx = *(const float4*)&mv[s];
    o.x = f2bf(sh.x + mx.x * dx.x); o.y = f2bf(sh.y + mx.y * dx.y);
    o.z = f2bf(sh.z + mx.z * dx.z); o.w = f2bf(sh.w + mx.w * dx.w);
    *(ushort4*)&Av[off] = o;
    mx = *(const float4*)&mr[s];
    o.x = f2bf(sh.x + mx.x * dx.x); o.y = f2bf(sh.y + mx.y * dx.y);
    o.z = f2bf(sh.z + mx.z * dx.z); o.w = f2bf(sh.w + mx.w * dx.w);
    *(ushort4*)&Ar[off] = o;
}

// ---------------- single-projection mix (fallback path) ----------------
__global__ __launch_bounds__(256)
void mix_kernel(const float* __restrict__ x, const float* __restrict__ mix,
                ushort* __restrict__ outA)
{
    const int idx = blockIdx.x * 256 + threadIdx.x;
    const int m = idx >> 8;
    const int s = (idx & 255) << 2;
    const float4 xv = *(const float4*)&x[(size_t)m * SD + s];
    float4 sh = make_float4(0.f, 0.f, 0.f, 0.f);
    if (m & (U_DIM - 1)) sh = *(const float4*)&x[(size_t)(m - 1) * SD + s];
    const float4 mx = *(const float4*)&mix[s];
    ushort4 o;
    o.x = f2bf(sh.x + mx.x * (xv.x - sh.x));
    o.y = f2bf(sh.y + mx.y * (xv.y - sh.y));
    o.z = f2bf(sh.z + mx.z * (xv.z - sh.z));
    o.w = f2bf(sh.w + mx.w * (xv.w - sh.w));
    *(ushort4*)&outA[(size_t)m * SD + s] = o;
}

// ======== 256x128 bf16 MFMA GEMM, 3-deep pipeline, ONE barrier per K-tile ========
// C[M,N] = A[M,K] @ (BT[N,K])^T + bias   M=8192, N=1024, K=1024
// FUSED==3: grid (32,8,3), z selects {k,v,r}; sigmoid at z==2; bf16 out
// FUSED==0: bf16 out  FUSED==1: bf16+sigmoid  FUSED==2: f32 out  (grid (32,8,1))
// 512 threads = 8 waves as 4M x 2N; wave tile 64x64 (4x4 16x16 frags in regs).
// Per K-tile (BK=64, 2 k-planes): 16 ds_read_b128 + 6 global_load_lds + 32 MFMA +
// ONE vmcnt(6) + ONE s_barrier. 3 LDS buffers (144 KB): stage tile t+2 during t.
// Ledger: 6 loads/tile; vmcnt(6) at tile end leaves only tile-t's 6 outstanding ->
// tile t-2 (read next... i.e. data for tile t+... staged 2 ahead) complete. WAR safe:
// buf[(t+2)%3] last read at tile t-1, reads retire into regs before that barrier.
// LDS row = 64B, 16B chunk q stored from source chunk q^((row>>1)&3) (0-conflict).
template<int FUSED>
__global__ __launch_bounds__(512)
void gemm_big(const ushort* __restrict__ Abase, const ushort* __restrict__ WTbase,
              const float* __restrict__ b0, const float* __restrict__ b1,
              const float* __restrict__ b2, void* __restrict__ Cbase)
{
    __shared__ ushort LA[3][2][256][32];   // 96 KB : [buf][kplane][row][32]
    __shared__ ushort LB[3][2][128][32];   // 48 KB

    const int tid = threadIdx.x;
    const int wv = tid >> 6, ln = tid & 63;
    const int wr = wv >> 1, wc = wv & 1;

    // bijective XCD swizzle (nwg: 768 or 256, both %8==0); mb fastest per XCD chunk
    const int nwg = (int)(gridDim.x * gridDim.y * gridDim.z);
    const int bid = (int)blockIdx.x +
                    (int)gridDim.x * ((int)blockIdx.y + (int)gridDim.y * (int)blockIdx.z);
    const int s_  = (bid & 7) * (nwg >> 3) + (bid >> 3);
    const int mb  = s_ & 31;
    const int nb  = (s_ >> 5) & 7;
    const int z   = s_ >> 8;
    const int m0 = mb * 256, n0 = nb * 128;

    const ushort* A; const ushort* BT; const float* bias; void* Cout; int dosig;
    if (FUSED == 3) {
        A    = Abase + (size_t)z * ((size_t)M_DIM * SD);
        BT   = WTbase + (size_t)z * ((size_t)SD * SD);
        bias = (z == 0) ? b0 : (z == 1) ? b1 : b2;
        Cout = (void*)((ushort*)Cbase + (size_t)z * ((size_t)M_DIM * SD));
        dosig = (z == 2);
    } else {
        A = Abase; BT = WTbase; bias = b0; Cout = Cbase; dosig = (FUSED == 1);
    }

    // ---- staging maps (linear LDS dest = tid*16B; inverse-swizzled global source) ----
    const int srow = tid >> 2;                                  // 0..127
    const int ssw  = ((tid & 3) ^ ((srow >> 1) & 3)) << 3;      // element offset in row
    const ushort* aSrc0 = A  + (size_t)(m0 + srow) * SD + ssw;
    const ushort* aSrc1 = aSrc0 + (size_t)128 * SD;
    const ushort* bSrc  = BT + (size_t)(n0 + srow) * SD + ssw;
    char* const laW = (char*)LA + wv * 1024;    // wave-uniform LDS bases
    char* const lbW = (char*)LB + wv * 1024;

    // ---- fragment-read maps (swizzled) ----
    const char* LAc = (const char*)LA;
    const char* LBc = (const char*)LB;
    const int lr  = ln & 15;
    const int lq  = ln >> 4;
    const int kof = ((lq ^ ((lr >> 1) & 3)) << 4);
    const int aRd = wr * 4096 + lr * 64 + kof;
    const int bRd = wc * 4096 + lr * 64 + kof;

    f32x4 acc[4][4];
    #pragma unroll
    for (int i = 0; i < 4; ++i)
        #pragma unroll
        for (int j = 0; j < 4; ++j)
            acc[i][j] = (f32x4){0.f, 0.f, 0.f, 0.f};

#define STG(bufS, ks, kt)                                                           \
    do { const int off = (kt) * 64 + (ks) * 32;                                     \
        __builtin_amdgcn_global_load_lds((glb_t*)(aSrc0 + off),                     \
            (lds_t*)(laW + (bufS) * 32768 + (ks) * 16384), 16, 0, 0);               \
        __builtin_amdgcn_global_load_lds((glb_t*)(aSrc1 + off),                     \
            (lds_t*)(laW + (bufS) * 32768 + (ks) * 16384 + 8192), 16, 0, 0);        \
        __builtin_amdgcn_global_load_lds((glb_t*)(bSrc + off),                      \
            (lds_t*)(lbW + (bufS) * 16384 + (ks) * 8192), 16, 0, 0);                \
    } while (0)

#define HALF(bR, ks)                                                                \
    do {                                                                            \
        short8 af[4], bq[4];                                                        \
        _Pragma("unroll")                                                           \
        for (int mt = 0; mt < 4; ++mt)                                              \
            af[mt] = *(const short8*)(LAc + (bR) * 32768 + (ks) * 16384             \
                                      + mt * 1024 + aRd);                           \
        _Pragma("unroll")                                                           \
        for (int nt = 0; nt < 4; ++nt)                                              \
            bq[nt] = *(const short8*)(LBc + (bR) * 16384 + (ks) * 8192              \
                                      + nt * 1024 + bRd);                           \
        __builtin_amdgcn_s_setprio(1);                                              \
        _Pragma("unroll")                                                           \
        for (int mt = 0; mt < 4; ++mt)                                              \
            _Pragma("unroll")                                                       \
            for (int nt = 0; nt < 4; ++nt)                                          \
                acc[mt][nt] = __builtin_amdgcn_mfma_f32_16x16x32_bf16(              \
                    af[mt], bq[nt], acc[mt][nt], 0, 0, 0);                          \
        __builtin_amdgcn_s_setprio(0);                                              \
    } while (0)

    // ---- prologue: stage tiles 0 and 1 fully (12 loads); tile0 (first 6) complete ----
    STG(0, 0, 0); STG(0, 1, 0);
    STG(1, 0, 1); STG(1, 1, 1);
    asm volatile("s_waitcnt vmcnt(6)" ::: "memory");
    __builtin_amdgcn_s_barrier();

    // ---- main loop: 16 K-tiles; ONE vmcnt(6) + ONE barrier per tile ----
    #pragma unroll
    for (int t = 0; t < 16; ++t) {
        const int bR = t % 3;
        const int tn = (t + 2 < 16) ? t + 2 : 15;   // clamped tail re-stage: never read
        const int bS = (t + 2) % 3;
        HALF(bR, 0);
        STG(bS, 0, tn);
        HALF(bR, 1);
        STG(bS, 1, tn);
        asm volatile("s_waitcnt vmcnt(6)" ::: "memory");
        __builtin_amdgcn_s_barrier();
    }

#undef HALF
#undef STG

    // ---- epilogue: frag row = lq*4 + j, col = lr (m89-verified) ----
    const int cr = lq * 4;
    const int cc = lr;
    #pragma unroll
    for (int mt = 0; mt < 4; ++mt)
    #pragma unroll
    for (int nt = 0; nt < 4; ++nt) {
        const int gc = n0 + wc * 64 + nt * 16 + cc;
        const float bv = bias[gc];
        #pragma unroll
        for (int j = 0; j < 4; ++j) {
            const int gr = m0 + wr * 64 + mt * 16 + cr + j;
            float v = acc[mt][nt][j] + bv;
            if (FUSED == 1 || FUSED == 3) { if (dosig) v = 1.f / (1.f + __expf(-v)); }
            if (FUSED == 2)
                ((float*)Cout)[(size_t)gr * SD + gc] = v;
            else
                ((ushort*)Cout)[(size_t)gr * SD + gc] = f2bf(v);
        }
    }
}

// ---------------- scan pass 1: per-chunk local states from zero init ----------------
__global__ __launch_bounds__(256)
void scan_local(const ushort* __restrict__ kq, const ushort* __restrict__ vq,
                const float* __restrict__ td,
                float* __restrict__ sa, float* __restrict__ sb, float* __restrict__ sp)
{
    const int idx = blockIdx.x * 256 + threadIdx.x;   // 8192*NC
    const int ch = idx & (M_DIM - 1);
    const int c  = idx >> 13;
    const int b  = ch >> 10, d = ch & (SD - 1);
    const float w = -__expf(td[d]);
    size_t ptr = (size_t)b * U_DIM * SD + (size_t)(c * CT) * SD + d;

    float a = 0.f, bb = 0.f, p = -1e38f;
    for (int s = 0; s < CT; ++s) {
        const float kt = bf2f(kq[ptr]), vt = bf2f(vq[ptr]);
        const float q2 = fmaxf(p + w, kt);
        const float e1 = __expf(p + w - q2);
        const float e2 = __expf(kt - q2);
        a = e1 * a + e2 * vt; bb = e1 * bb + e2; p = q2;
        ptr += SD;
    }
    sa[idx] = a; sb[idx] = bb; sp[idx] = p;
}

// ---------------- scan pass 2: sequential prefix-combine over chunks ----------------
__global__ __launch_bounds__(256)
void scan_prefix(const float* __restrict__ td,
                 float* __restrict__ sa, float* __restrict__ sb, float* __restrict__ sp)
{
    const int ch = blockIdx.x * 256 + threadIdx.x;    // 8192
    const float wT = -__expf(td[ch & (SD - 1)]) * (float)CT;
    float ca = 0.f, cb = 0.f, cp = -1e38f;
    for (int c = 0; c < NC; ++c) {
        const int i = c * M_DIM + ch;
        const float la = sa[i], lb = sb[i], lp = sp[i];
        sa[i] = ca; sb[i] = cb; sp[i] = cp;
        const float pd = cp + wT;                      // decay carry across chunk
        const float q  = fmaxf(pd, lp);
        const float e1 = __expf(pd - q);
        const float e2 = __expf(lp - q);
        ca = e1 * ca + e2 * la; cb = e1 * cb + e2 * lb; cp = q;
    }
}

// ---------------- scan pass 3: outputs r*wkv (bf16) from incoming states ----------------
__global__ __launch_bounds__(256)
void scan_out(const ushort* __restrict__ kq, const ushort* __restrict__ vq,
              const ushort* __restrict__ rq,
              const float* __restrict__ td, const float* __restrict__ tfirst,
              const float* __restrict__ sa, const float* __restrict__ sb,
              const float* __restrict__ sp,
              ushort* __restrict__ rw)
{
    const int idx = blockIdx.x * 256 + threadIdx.x;
    const int ch = idx & (M_DIM - 1);
    const int c  = idx >> 13;
    const int b  = ch >> 10, d = ch & (SD - 1);
    const float w  = -__expf(td[d]);
    const float tf = tfirst[d];
    size_t ptr = (size_t)b * U_DIM * SD + (size_t)(c * CT) * SD + d;

    float a = sa[idx], bb = sb[idx], p = sp[idx];
    for (int s = 0; s < CT; ++s) {
        const float kt = bf2f(kq[ptr]), vt = bf2f(vq[ptr]), rt = bf2f(rq[ptr]);
        const float q  = fmaxf(p, tf + kt);
        const float e1 = __expf(p - q);
        const float e2 = __expf(tf + kt - q);
        const float ov = (e1 * a + e2 * vt) * __builtin_amdgcn_rcpf(e1 * bb + e2);
        const float q2  = fmaxf(p + w, kt);
        const float e1b = __expf(p + w - q2);
        const float e2b = __expf(kt - q2);
        a = e1b * a + e2b * vt; bb = e1b * bb + e2b; p = q2;
        rw[ptr] = f2bf(rt * ov);
        ptr += SD;
    }
}

extern "C" void kernel_launch(void* const* d_in, const int* in_sizes, int n_in,
                              void* d_out, int out_size, void* d_ws, size_t ws_size,
                              hipStream_t stream)
{
    (void)in_sizes; (void)n_in; (void)out_size;
    const float* x  = (const float*)d_in[0];
    const float* td = (const float*)d_in[1];
    const float* tf = (const float*)d_in[2];
    const float* mk = (const float*)d_in[3];
    const float* mv = (const float*)d_in[4];
    const float* mr = (const float*)d_in[5];
    const float* Wk = (const float*)d_in[6];
    const float* bk = (const float*)d_in[7];
    const float* Wv = (const float*)d_in[8];
    const float* bv = (const float*)d_in[9];
    const float* Wr = (const float*)d_in[10];
    const float* br = (const float*)d_in[11];
    const float* Wo = (const float*)d_in[12];
    const float* bo = (const float*)d_in[13];
    float* out = (float*)d_out;

    const size_t NE = (size_t)M_DIM * SD;   // 8M elements
    const size_t WS = (size_t)SD * SD;
    char* ws = (char*)d_ws;

    const dim3 gg1(32, 8, 1);
    const dim3 gg3(32, 8, 3);

    if (ws_size >= ((size_t)108 << 20)) {
        // fused layout: WT 0-8 | Ak 8-24 | Av 24-40 | Ar 40-56 | k 56-72 | v 72-88 |
        //               r 88-104 | states 104-107  (MB)
        ushort* WT  = (ushort*)ws;
        ushort* Ak  = (ushort*)(ws + ((size_t)8   << 20));
        ushort* kvr = (ushort*)(ws + ((size_t)56  << 20));
        float*  sa  = (float*)(ws + ((size_t)104 << 20));
        float*  sb  = (float*)(ws + ((size_t)105 << 20));
        float*  sp  = (float*)(ws + ((size_t)106 << 20));
        ushort* kbuf = kvr;
        ushort* vbuf = kvr + NE;
        ushort* rbuf = kvr + 2 * NE;
        ushort* rwkv = Ak;                  // A-buffers dead after proj GEMM

        wtrans_kernel<<<dim3(32, 32, 4), 256, 0, stream>>>(Wk, Wv, Wr, Wo, WT);
        mix3_kernel<<<8192, 256, 0, stream>>>(x, mk, mv, mr, Ak, Ak + NE, Ak + 2 * NE);
        gemm_big<3><<<gg3, 512, 0, stream>>>(Ak, WT, bk, bv, br, kvr);

        scan_local <<<(M_DIM * NC) / 256, 256, 0, stream>>>(kbuf, vbuf, td, sa, sb, sp);
        scan_prefix<<<M_DIM / 256, 256, 0, stream>>>(td, sa, sb, sp);
        scan_out   <<<(M_DIM * NC) / 256, 256, 0, stream>>>(kbuf, vbuf, rbuf, td, tf,
                                                            sa, sb, sp, rwkv);

        gemm_big<2><<<gg1, 512, 0, stream>>>(rwkv, WT + 3 * WS, bo, bo, bo, out);
    } else {
        // sequential layout (75 MB)
        ushort* WT   = (ushort*)ws;
        ushort* Abuf = (ushort*)(ws + ((size_t)8  << 20));
        ushort* kbuf = (ushort*)(ws + ((size_t)24 << 20));
        ushort* vbuf = (ushort*)(ws + ((size_t)40 << 20));
        ushort* rbuf = (ushort*)(ws + ((size_t)56 << 20));
        float*  sa   = (float*)(ws + ((size_t)72 << 20));
        float*  sb   = (float*)(ws + ((size_t)73 << 20));
        float*  sp   = (float*)(ws + ((size_t)74 << 20));
        ushort* rwkv = Abuf;

        wtrans_kernel<<<dim3(32, 32, 4), 256, 0, stream>>>(Wk, Wv, Wr, Wo, WT);
        mix_kernel<<<8192, 256, 0, stream>>>(x, mk, Abuf);
        gemm_big<0><<<gg1, 512, 0, stream>>>(Abuf, WT, bk, bk, bk, kbuf);
        mix_kernel<<<8192, 256, 0, stream>>>(x, mv, Abuf);
        gemm_big<0><<<gg1, 512, 0, stream>>>(Abuf, WT + WS, bv, bv, bv, vbuf);
        mix_kernel<<<8192, 256, 0, stream>>>(x, mr, Abuf);
        gemm_big<1><<<gg1, 512, 0, stream>>>(Abuf, WT + 2 * WS, br, br, br, rbuf);

        scan_local <<<(M_DIM * NC) / 256, 256, 0, stream>>>(kbuf, vbuf, td, sa, sb, sp);
        scan_prefix<<<M_DIM / 256, 256, 0, stream>>>(td, sa, sb, sp);
        scan_out   <<<(M_DIM * NC) / 256, 256, 0, stream>>>(kbuf, vbuf, rbuf, td, tf,
                                                            sa, sb, sp, rwkv);

        gemm_big<2><<<gg1, 512, 0, stream>>>(rwkv, WT + 3 * WS, bo, bo, bo, out);
    }
}

// Round 7
// 148.265 us; speedup vs baseline: 1.2510x; 1.1380x over previous
//
#include <hip/hip_runtime.h>
#include <cstdint>
#include <cstddef>

#define B_DIM 8
#define U_DIM 1024
#define SD    1024                 // SIZE == D_ATT == 1024
#define M_DIM (B_DIM * U_DIM)      // 8192 rows; also B*D channel count
#define NC 32                      // scan chunks
#define CT 32                      // tokens per chunk (NC*CT == U_DIM)

typedef __attribute__((ext_vector_type(8))) short short8;
typedef __attribute__((ext_vector_type(4))) float f32x4;

typedef __attribute__((address_space(3))) void       lds_t;
typedef const __attribute__((address_space(1))) void glb_t;

__device__ __forceinline__ ushort f2bf(float f) {
    union { float f; uint32_t u; } c; c.f = f;
    uint32_t r = (c.u + 0x7FFFu + ((c.u >> 16) & 1u)) >> 16;   // RNE
    return (ushort)r;
}
__device__ __forceinline__ float bf2f(ushort h) {
    union { float f; uint32_t u; } c; c.u = ((uint32_t)h) << 16; return c.f;
}

// ---------------- prepass: W[K][N] f32 -> W^T[N][K] bf16, 4 matrices ----------------
__global__ __launch_bounds__(256)
void wtrans_kernel(const float* __restrict__ Wk, const float* __restrict__ Wv,
                   const float* __restrict__ Wr, const float* __restrict__ Wo,
                   ushort* __restrict__ WT)
{
    __shared__ float t[32][33];
    const float* W = (blockIdx.z == 0) ? Wk : (blockIdx.z == 1) ? Wv
                   : (blockIdx.z == 2) ? Wr : Wo;
    ushort* o = WT + (size_t)blockIdx.z * SD * SD;
    const int tx = threadIdx.x & 31, ty = threadIdx.x >> 5;
    const int k0 = blockIdx.y * 32, n0 = blockIdx.x * 32;
    #pragma unroll
    for (int i = 0; i < 4; ++i)
        t[ty + i * 8][tx] = W[(size_t)(k0 + ty + i * 8) * SD + n0 + tx];
    __syncthreads();
    #pragma unroll
    for (int i = 0; i < 4; ++i)
        o[(size_t)(n0 + ty + i * 8) * SD + k0 + tx] = f2bf(t[tx][ty + i * 8]);
}

// ---------------- prepass: A_j = sh + mix_j*(x - sh), bf16, all three in one pass ----
__global__ __launch_bounds__(256)
void mix3_kernel(const float* __restrict__ x,
                 const float* __restrict__ mk, const float* __restrict__ mv,
                 const float* __restrict__ mr,
                 ushort* __restrict__ Ak, ushort* __restrict__ Av,
                 ushort* __restrict__ Ar)
{
    const int idx = blockIdx.x * 256 + threadIdx.x;  // 2M groups of 4
    const int m = idx >> 8;
    const int s = (idx & 255) << 2;
    const float4 xv = *(const float4*)&x[(size_t)m * SD + s];
    float4 sh = make_float4(0.f, 0.f, 0.f, 0.f);
    if (m & (U_DIM - 1)) sh = *(const float4*)&x[(size_t)(m - 1) * SD + s];
    const float4 dx = make_float4(xv.x - sh.x, xv.y - sh.y, xv.z - sh.z, xv.w - sh.w);
    const size_t off = (size_t)m * SD + s;

    float4 mx;
    ushort4 o;
    mx = *(const float4*)&mk[s];
    o.x = f2bf(sh.x + mx.x * dx.x); o.y = f2bf(sh.y + mx.y * dx.y);
    o.z = f2bf(sh.z + mx.z * dx.z); o.w = f2bf(sh.w + mx.w * dx.w);
    *(ushort4*)&Ak[off] = o;
    mx = *(const float4*)&mv[s];
    o.x = f2bf(sh.x + mx.x * dx.x); o.y = f2bf(sh.y + mx.y * dx.y);
    o.z = f2bf(sh.z + mx.z * dx.z); o.w = f2bf(sh.w + mx.w * dx.w);
    *(ushort4*)&Av[off] = o;
    mx = *(const float4*)&mr[s];
    o.x = f2bf(sh.x + mx.x * dx.x); o.y = f2bf(sh.y + mx.y * dx.y);
    o.z = f2bf(sh.z + mx.z * dx.z); o.w = f2bf(sh.w + mx.w * dx.w);
    *(ushort4*)&Ar[off] = o;
}

// ---------------- single-projection mix (fallback path) ----------------
__global__ __launch_bounds__(256)
void mix_kernel(const float* __restrict__ x, const float* __restrict__ mix,
                ushort* __restrict__ outA)
{
    const int idx = blockIdx.x * 256 + threadIdx.x;
    const int m = idx >> 8;
    const int s = (idx & 255) << 2;
    const float4 xv = *(const float4*)&x[(size_t)m * SD + s];
    float4 sh = make_float4(0.f, 0.f, 0.f, 0.f);
    if (m & (U_DIM - 1)) sh = *(const float4*)&x[(size_t)(m - 1) * SD + s];
    const float4 mx = *(const float4*)&mix[s];
    ushort4 o;
    o.x = f2bf(sh.x + mx.x * (xv.x - sh.x));
    o.y = f2bf(sh.y + mx.y * (xv.y - sh.y));
    o.z = f2bf(sh.z + mx.z * (xv.z - sh.z));
    o.w = f2bf(sh.w + mx.w * (xv.w - sh.w));
    *(ushort4*)&outA[(size_t)m * SD + s] = o;
}

// ======== 128x128 bf16 MFMA GEMM — m97-exact drain loop, residency-maximized ========
// C[M,N] = A[M,K] @ (BT[N,K])^T + bias   M=8192, K=1024
// FUSED==3: grid (64,24): z = by>>3 selects {k,v,r}; sigmoid at z==2; bf16 out
// FUSED==0/1: grid (64,8): bf16 out (1: +sigmoid)      FUSED==2: f32 out
// 256 threads = 4 waves (2M x 2N), wave tile 64x64 (4x4 16x16 frags).
// SINGLE 16 KB LDS buffer (As 8K + Bs 8K) -> up to 10 blocks/CU by LDS; VGPR ~84
// -> ~6 by RF; grid supplies 6/CU. Loop: STAGE -> syncthreads (drains vmcnt=0,
// compiler) -> 16 MFMA -> syncthreads. Cross-block wave overlap (m114) hides the
// drain: this is what gave m97 874 TF at 3 blocks/CU.
// LDS row = 64 B; 16B chunk q stored from source chunk q^((row>>1)&3) (0-conflict,
// verified rounds 3-6); fragment reads apply the same XOR.
template<int FUSED>
__global__ __launch_bounds__(256)
void gemm128(const ushort* __restrict__ Abase, const ushort* __restrict__ WTbase,
             const float* __restrict__ b0, const float* __restrict__ b1,
             const float* __restrict__ b2, void* __restrict__ Cbase)
{
    __shared__ ushort As[128 * 32];   // 8 KB  [row][32k], 64 B rows
    __shared__ ushort Bs[128 * 32];   // 8 KB

    const int tid = threadIdx.x;
    const int wv = tid >> 6, ln = tid & 63;
    const int wm = (wv >> 1) * 64, wn = (wv & 1) * 64;

    const int m0 = blockIdx.x * 128;
    int nb = (int)blockIdx.y, z = 0;
    if (FUSED == 3) { z = nb >> 3; nb &= 7; }
    const int n0 = nb * 128;

    const ushort* A; const ushort* BT; const float* bias; void* Cout; int dosig;
    if (FUSED == 3) {
        A    = Abase + (size_t)z * ((size_t)M_DIM * SD);
        BT   = WTbase + (size_t)z * ((size_t)SD * SD);
        bias = (z == 0) ? b0 : (z == 1) ? b1 : b2;
        Cout = (void*)((ushort*)Cbase + (size_t)z * ((size_t)M_DIM * SD));
        dosig = (z == 2);
    } else {
        A = Abase; BT = WTbase; bias = b0; Cout = Cbase; dosig = (FUSED == 1);
    }

    // ---- staging maps (linear LDS dest = chunk*16B; inverse-swizzled global src) ----
    const int srow = tid >> 2;                                 // 0..63 (+64 2nd round)
    const int sq   = ((tid & 3) ^ ((srow >> 1) & 3)) << 3;     // elem offset in row
    const ushort* aS = A  + (size_t)(m0 + srow) * SD + sq;
    const ushort* bS = BT + (size_t)(n0 + srow) * SD + sq;
    char* const laW = (char*)As + wv * 1024;                   // wave-uniform bases
    char* const lbW = (char*)Bs + wv * 1024;

    // ---- fragment-read maps (swizzled) ----
    const int lr  = ln & 15;
    const int lq  = ln >> 4;
    const int kof = (lq ^ ((lr >> 1) & 3)) << 4;               // byte offset of chunk
    const char* LAc = (const char*)As;
    const char* LBc = (const char*)Bs;
    const int aRd = wm * 64 + lr * 64 + kof;
    const int bRd = wn * 64 + lr * 64 + kof;

    f32x4 acc[4][4];
    #pragma unroll
    for (int i = 0; i < 4; ++i)
        #pragma unroll
        for (int j = 0; j < 4; ++j)
            acc[i][j] = (f32x4){0.f, 0.f, 0.f, 0.f};

    for (int k0 = 0; k0 < SD; k0 += 32) {
        // ---- stage tile (4 global_load_lds per wave) ----
        __builtin_amdgcn_global_load_lds((glb_t*)(aS + k0),                 (lds_t*)laW,          16, 0, 0);
        __builtin_amdgcn_global_load_lds((glb_t*)(aS + (size_t)64 * SD + k0), (lds_t*)(laW + 4096), 16, 0, 0);
        __builtin_amdgcn_global_load_lds((glb_t*)(bS + k0),                 (lds_t*)lbW,          16, 0, 0);
        __builtin_amdgcn_global_load_lds((glb_t*)(bS + (size_t)64 * SD + k0), (lds_t*)(lbW + 4096), 16, 0, 0);
        __syncthreads();   // compiler drains vmcnt(0) before s_barrier

        short8 af[4], bq[4];
        #pragma unroll
        for (int mt = 0; mt < 4; ++mt)
            af[mt] = *(const short8*)(LAc + mt * 1024 + aRd);
        #pragma unroll
        for (int nt = 0; nt < 4; ++nt)
            bq[nt] = *(const short8*)(LBc + nt * 1024 + bRd);
        #pragma unroll
        for (int mt = 0; mt < 4; ++mt)
            #pragma unroll
            for (int nt = 0; nt < 4; ++nt)
                acc[mt][nt] = __builtin_amdgcn_mfma_f32_16x16x32_bf16(
                    af[mt], bq[nt], acc[mt][nt], 0, 0, 0);
        __syncthreads();
    }

    // ---- epilogue: frag row = lq*4 + j, col = lr (m89-verified) ----
    const int cr = lq * 4;
    const int cc = lr;
    #pragma unroll
    for (int mt = 0; mt < 4; ++mt)
    #pragma unroll
    for (int nt = 0; nt < 4; ++nt) {
        const int gc = n0 + wn + nt * 16 + cc;
        const float bv = bias[gc];
        #pragma unroll
        for (int j = 0; j < 4; ++j) {
            const int gr = m0 + wm + mt * 16 + cr + j;
            float v = acc[mt][nt][j] + bv;
            if (FUSED == 1 || FUSED == 3) { if (dosig) v = 1.f / (1.f + __expf(-v)); }
            if (FUSED == 2)
                ((float*)Cout)[(size_t)gr * SD + gc] = v;
            else
                ((ushort*)Cout)[(size_t)gr * SD + gc] = f2bf(v);
        }
    }
}

// ---------------- scan pass 1: per-chunk local states from zero init ----------------
__global__ __launch_bounds__(256)
void scan_local(const ushort* __restrict__ kq, const ushort* __restrict__ vq,
                const float* __restrict__ td,
                float* __restrict__ sa, float* __restrict__ sb, float* __restrict__ sp)
{
    const int idx = blockIdx.x * 256 + threadIdx.x;   // 8192*NC
    const int ch = idx & (M_DIM - 1);
    const int c  = idx >> 13;
    const int b  = ch >> 10, d = ch & (SD - 1);
    const float w = -__expf(td[d]);
    size_t ptr = (size_t)b * U_DIM * SD + (size_t)(c * CT) * SD + d;

    float a = 0.f, bb = 0.f, p = -1e38f;
    for (int s = 0; s < CT; ++s) {
        const float kt = bf2f(kq[ptr]), vt = bf2f(vq[ptr]);
        const float q2 = fmaxf(p + w, kt);
        const float e1 = __expf(p + w - q2);
        const float e2 = __expf(kt - q2);
        a = e1 * a + e2 * vt; bb = e1 * bb + e2; p = q2;
        ptr += SD;
    }
    sa[idx] = a; sb[idx] = bb; sp[idx] = p;
}

// ---------------- scan pass 2: sequential prefix-combine over chunks ----------------
__global__ __launch_bounds__(256)
void scan_prefix(const float* __restrict__ td,
                 float* __restrict__ sa, float* __restrict__ sb, float* __restrict__ sp)
{
    const int ch = blockIdx.x * 256 + threadIdx.x;    // 8192
    const float wT = -__expf(td[ch & (SD - 1)]) * (float)CT;
    float ca = 0.f, cb = 0.f, cp = -1e38f;
    for (int c = 0; c < NC; ++c) {
        const int i = c * M_DIM + ch;
        const float la = sa[i], lb = sb[i], lp = sp[i];
        sa[i] = ca; sb[i] = cb; sp[i] = cp;
        const float pd = cp + wT;                      // decay carry across chunk
        const float q  = fmaxf(pd, lp);
        const float e1 = __expf(pd - q);
        const float e2 = __expf(lp - q);
        ca = e1 * ca + e2 * la; cb = e1 * cb + e2 * lb; cp = q;
    }
}

// ---------------- scan pass 3: outputs r*wkv (bf16) from incoming states ----------------
__global__ __launch_bounds__(256)
void scan_out(const ushort* __restrict__ kq, const ushort* __restrict__ vq,
              const ushort* __restrict__ rq,
              const float* __restrict__ td, const float* __restrict__ tfirst,
              const float* __restrict__ sa, const float* __restrict__ sb,
              const float* __restrict__ sp,
              ushort* __restrict__ rw)
{
    const int idx = blockIdx.x * 256 + threadIdx.x;
    const int ch = idx & (M_DIM - 1);
    const int c  = idx >> 13;
    const int b  = ch >> 10, d = ch & (SD - 1);
    const float w  = -__expf(td[d]);
    const float tf = tfirst[d];
    size_t ptr = (size_t)b * U_DIM * SD + (size_t)(c * CT) * SD + d;

    float a = sa[idx], bb = sb[idx], p = sp[idx];
    for (int s = 0; s < CT; ++s) {
        const float kt = bf2f(kq[ptr]), vt = bf2f(vq[ptr]), rt = bf2f(rq[ptr]);
        const float q  = fmaxf(p, tf + kt);
        const float e1 = __expf(p - q);
        const float e2 = __expf(tf + kt - q);
        const float ov = (e1 * a + e2 * vt) * __builtin_amdgcn_rcpf(e1 * bb + e2);
        const float q2  = fmaxf(p + w, kt);
        const float e1b = __expf(p + w - q2);
        const float e2b = __expf(kt - q2);
        a = e1b * a + e2b * vt; bb = e1b * bb + e2b; p = q2;
        rw[ptr] = f2bf(rt * ov);
        ptr += SD;
    }
}

extern "C" void kernel_launch(void* const* d_in, const int* in_sizes, int n_in,
                              void* d_out, int out_size, void* d_ws, size_t ws_size,
                              hipStream_t stream)
{
    (void)in_sizes; (void)n_in; (void)out_size;
    const float* x  = (const float*)d_in[0];
    const float* td = (const float*)d_in[1];
    const float* tf = (const float*)d_in[2];
    const float* mk = (const float*)d_in[3];
    const float* mv = (const float*)d_in[4];
    const float* mr = (const float*)d_in[5];
    const float* Wk = (const float*)d_in[6];
    const float* bk = (const float*)d_in[7];
    const float* Wv = (const float*)d_in[8];
    const float* bv = (const float*)d_in[9];
    const float* Wr = (const float*)d_in[10];
    const float* br = (const float*)d_in[11];
    const float* Wo = (const float*)d_in[12];
    const float* bo = (const float*)d_in[13];
    float* out = (float*)d_out;

    const size_t NE = (size_t)M_DIM * SD;   // 8M elements
    const size_t WS = (size_t)SD * SD;
    char* ws = (char*)d_ws;

    const dim3 gg1(64, 8, 1);
    const dim3 gg3(64, 24, 1);

    if (ws_size >= ((size_t)108 << 20)) {
        // fused layout: WT 0-8 | Ak 8-24 | Av 24-40 | Ar 40-56 | k 56-72 | v 72-88 |
        //               r 88-104 | states 104-107  (MB)
        ushort* WT  = (ushort*)ws;
        ushort* Ak  = (ushort*)(ws + ((size_t)8   << 20));
        ushort* kvr = (ushort*)(ws + ((size_t)56  << 20));
        float*  sa  = (float*)(ws + ((size_t)104 << 20));
        float*  sb  = (float*)(ws + ((size_t)105 << 20));
        float*  sp  = (float*)(ws + ((size_t)106 << 20));
        ushort* kbuf = kvr;
        ushort* vbuf = kvr + NE;
        ushort* rbuf = kvr + 2 * NE;
        ushort* rwkv = Ak;                  // A-buffers dead after proj GEMM

        wtrans_kernel<<<dim3(32, 32, 4), 256, 0, stream>>>(Wk, Wv, Wr, Wo, WT);
        mix3_kernel<<<8192, 256, 0, stream>>>(x, mk, mv, mr, Ak, Ak + NE, Ak + 2 * NE);
        gemm128<3><<<gg3, 256, 0, stream>>>(Ak, WT, bk, bv, br, kvr);

        scan_local <<<(M_DIM * NC) / 256, 256, 0, stream>>>(kbuf, vbuf, td, sa, sb, sp);
        scan_prefix<<<M_DIM / 256, 256, 0, stream>>>(td, sa, sb, sp);
        scan_out   <<<(M_DIM * NC) / 256, 256, 0, stream>>>(kbuf, vbuf, rbuf, td, tf,
                                                            sa, sb, sp, rwkv);

        gemm128<2><<<gg1, 256, 0, stream>>>(rwkv, WT + 3 * WS, bo, bo, bo, out);
    } else {
        // sequential layout (75 MB)
        ushort* WT   = (ushort*)ws;
        ushort* Abuf = (ushort*)(ws + ((size_t)8  << 20));
        ushort* kbuf = (ushort*)(ws + ((size_t)24 << 20));
        ushort* vbuf = (ushort*)(ws + ((size_t)40 << 20));
        ushort* rbuf = (ushort*)(ws + ((size_t)56 << 20));
        float*  sa   = (float*)(ws + ((size_t)72 << 20));
        float*  sb   = (float*)(ws + ((size_t)73 << 20));
        float*  sp   = (float*)(ws + ((size_t)74 << 20));
        ushort* rwkv = Abuf;

        wtrans_kernel<<<dim3(32, 32, 4), 256, 0, stream>>>(Wk, Wv, Wr, Wo, WT);
        mix_kernel<<<8192, 256, 0, stream>>>(x, mk, Abuf);
        gemm128<0><<<gg1, 256, 0, stream>>>(Abuf, WT, bk, bk, bk, kbuf);
        mix_kernel<<<8192, 256, 0, stream>>>(x, mv, Abuf);
        gemm128<0><<<gg1, 256, 0, stream>>>(Abuf, WT + WS, bv, bv, bv, vbuf);
        mix_kernel<<<8192, 256, 0, stream>>>(x, mr, Abuf);
        gemm128<1><<<gg1, 256, 0, stream>>>(Abuf, WT + 2 * WS, br, br, br, rbuf);

        scan_local <<<(M_DIM * NC) / 256, 256, 0, stream>>>(kbuf, vbuf, td, sa, sb, sp);
        scan_prefix<<<M_DIM / 256, 256, 0, stream>>>(td, sa, sb, sp);
        scan_out   <<<(M_DIM * NC) / 256, 256, 0, stream>>>(kbuf, vbuf, rbuf, td, tf,
                                                            sa, sb, sp, rwkv);

        gemm128<2><<<gg1, 256, 0, stream>>>(rwkv, WT + 3 * WS, bo, bo, bo, out);
    }
}

// Round 8
// 146.482 us; speedup vs baseline: 1.2663x; 1.0122x over previous
//
#include <hip/hip_runtime.h>
#include <cstdint>
#include <cstddef>

#define B_DIM 8
#define U_DIM 1024
#define SD    1024                 // SIZE == D_ATT == 1024
#define M_DIM (B_DIM * U_DIM)      // 8192 rows; also B*D channel count
#define NC 32                      // scan chunks
#define CT 32                      // tokens per chunk (NC*CT == U_DIM)

typedef __attribute__((ext_vector_type(8))) short short8;
typedef __attribute__((ext_vector_type(4))) float f32x4;

typedef __attribute__((address_space(3))) void       lds_t;
typedef const __attribute__((address_space(1))) void glb_t;

__device__ __forceinline__ ushort f2bf(float f) {
    union { float f; uint32_t u; } c; c.f = f;
    uint32_t r = (c.u + 0x7FFFu + ((c.u >> 16) & 1u)) >> 16;   // RNE
    return (ushort)r;
}
__device__ __forceinline__ float bf2f(ushort h) {
    union { float f; uint32_t u; } c; c.u = ((uint32_t)h) << 16; return c.f;
}

// ---------------- prepass: W[K][N] f32 -> W^T[N][K] bf16, 4 matrices ----------------
__global__ __launch_bounds__(256)
void wtrans_kernel(const float* __restrict__ Wk, const float* __restrict__ Wv,
                   const float* __restrict__ Wr, const float* __restrict__ Wo,
                   ushort* __restrict__ WT)
{
    __shared__ float t[32][33];
    const float* W = (blockIdx.z == 0) ? Wk : (blockIdx.z == 1) ? Wv
                   : (blockIdx.z == 2) ? Wr : Wo;
    ushort* o = WT + (size_t)blockIdx.z * SD * SD;
    const int tx = threadIdx.x & 31, ty = threadIdx.x >> 5;
    const int k0 = blockIdx.y * 32, n0 = blockIdx.x * 32;
    #pragma unroll
    for (int i = 0; i < 4; ++i)
        t[ty + i * 8][tx] = W[(size_t)(k0 + ty + i * 8) * SD + n0 + tx];
    __syncthreads();
    #pragma unroll
    for (int i = 0; i < 4; ++i)
        o[(size_t)(n0 + ty + i * 8) * SD + k0 + tx] = f2bf(t[tx][ty + i * 8]);
}

// ---------------- prepass: A_j = sh + mix_j*(x - sh), bf16, all three in one pass ----
__global__ __launch_bounds__(256)
void mix3_kernel(const float* __restrict__ x,
                 const float* __restrict__ mk, const float* __restrict__ mv,
                 const float* __restrict__ mr,
                 ushort* __restrict__ Ak, ushort* __restrict__ Av,
                 ushort* __restrict__ Ar)
{
    const int idx = blockIdx.x * 256 + threadIdx.x;  // 2M groups of 4
    const int m = idx >> 8;
    const int s = (idx & 255) << 2;
    const float4 xv = *(const float4*)&x[(size_t)m * SD + s];
    float4 sh = make_float4(0.f, 0.f, 0.f, 0.f);
    if (m & (U_DIM - 1)) sh = *(const float4*)&x[(size_t)(m - 1) * SD + s];
    const float4 dx = make_float4(xv.x - sh.x, xv.y - sh.y, xv.z - sh.z, xv.w - sh.w);
    const size_t off = (size_t)m * SD + s;

    float4 mx;
    ushort4 o;
    mx = *(const float4*)&mk[s];
    o.x = f2bf(sh.x + mx.x * dx.x); o.y = f2bf(sh.y + mx.y * dx.y);
    o.z = f2bf(sh.z + mx.z * dx.z); o.w = f2bf(sh.w + mx.w * dx.w);
    *(ushort4*)&Ak[off] = o;
    mx = *(const float4*)&mv[s];
    o.x = f2bf(sh.x + mx.x * dx.x); o.y = f2bf(sh.y + mx.y * dx.y);
    o.z = f2bf(sh.z + mx.z * dx.z); o.w = f2bf(sh.w + mx.w * dx.w);
    *(ushort4*)&Av[off] = o;
    mx = *(const float4*)&mr[s];
    o.x = f2bf(sh.x + mx.x * dx.x); o.y = f2bf(sh.y + mx.y * dx.y);
    o.z = f2bf(sh.z + mx.z * dx.z); o.w = f2bf(sh.w + mx.w * dx.w);
    *(ushort4*)&Ar[off] = o;
}

// ---------------- single-projection mix (fallback path) ----------------
__global__ __launch_bounds__(256)
void mix_kernel(const float* __restrict__ x, const float* __restrict__ mix,
                ushort* __restrict__ outA)
{
    const int idx = blockIdx.x * 256 + threadIdx.x;
    const int m = idx >> 8;
    const int s = (idx & 255) << 2;
    const float4 xv = *(const float4*)&x[(size_t)m * SD + s];
    float4 sh = make_float4(0.f, 0.f, 0.f, 0.f);
    if (m & (U_DIM - 1)) sh = *(const float4*)&x[(size_t)(m - 1) * SD + s];
    const float4 mx = *(const float4*)&mix[s];
    ushort4 o;
    o.x = f2bf(sh.x + mx.x * (xv.x - sh.x));
    o.y = f2bf(sh.y + mx.y * (xv.y - sh.y));
    o.z = f2bf(sh.z + mx.z * (xv.z - sh.z));
    o.w = f2bf(sh.w + mx.w * (xv.w - sh.w));
    *(ushort4*)&outA[(size_t)m * SD + s] = o;
}

// ======== 128x128 bf16 MFMA GEMM — drain loop, BK=64, residency-maximized ========
// C[M,N] = A[M,K] @ (BT[N,K])^T + bias   M=8192, K=1024
// FUSED==3: grid (64,24): z = by>>3 selects {k,v,r}; sigmoid at z==2; bf16 out
// FUSED==0/1: grid (64,8): bf16 out (1: +sigmoid)      FUSED==2: f32 out
// 256 threads = 4 waves (2M x 2N), wave tile 64x64 (4x4 16x16 frags).
// SINGLE 32 KB LDS buffer: per operand [2 kplanes][128 rows][32 elems] (64B rows).
// Per K-tile (BK=64): 8 global_load_lds + ONE syncthreads drain + 2 k-plane halves
// of {8 ds_read_b128 + 16 MFMA} + barrier -> 16 drains total (vs 32 at BK=32,
// round 7: 554 TF). Cross-block wave overlap (4 blocks/CU) fills the drain stall.
// LDS 16B chunk q stored from source chunk q^((row>>1)&3) (0-conflict, rounds 3-7);
// fragment reads apply the same XOR.
template<int FUSED>
__global__ __launch_bounds__(256)
void gemm128(const ushort* __restrict__ Abase, const ushort* __restrict__ WTbase,
             const float* __restrict__ b0, const float* __restrict__ b1,
             const float* __restrict__ b2, void* __restrict__ Cbase)
{
    __shared__ ushort As[2 * 128 * 32];   // 16 KB  [plane][row][32k], 64 B rows
    __shared__ ushort Bs[2 * 128 * 32];   // 16 KB

    const int tid = threadIdx.x;
    const int wv = tid >> 6, ln = tid & 63;
    const int wm = (wv >> 1) * 64, wn = (wv & 1) * 64;

    const int m0 = blockIdx.x * 128;
    int nb = (int)blockIdx.y, z = 0;
    if (FUSED == 3) { z = nb >> 3; nb &= 7; }
    const int n0 = nb * 128;

    const ushort* A; const ushort* BT; const float* bias; void* Cout; int dosig;
    if (FUSED == 3) {
        A    = Abase + (size_t)z * ((size_t)M_DIM * SD);
        BT   = WTbase + (size_t)z * ((size_t)SD * SD);
        bias = (z == 0) ? b0 : (z == 1) ? b1 : b2;
        Cout = (void*)((ushort*)Cbase + (size_t)z * ((size_t)M_DIM * SD));
        dosig = (z == 2);
    } else {
        A = Abase; BT = WTbase; bias = b0; Cout = Cbase; dosig = (FUSED == 1);
    }

    // ---- staging maps (linear LDS dest = chunk*16B; inverse-swizzled global src) ----
    const int srow = tid >> 2;                                 // 0..63 (+64 2nd issue)
    const int sq   = ((tid & 3) ^ ((srow >> 1) & 3)) << 3;     // elem offset in row
    const ushort* aS = A  + (size_t)(m0 + srow) * SD + sq;
    const ushort* bS = BT + (size_t)(n0 + srow) * SD + sq;
    char* const laW = (char*)As + wv * 1024;                   // wave-uniform bases
    char* const lbW = (char*)Bs + wv * 1024;

    // ---- fragment-read maps (swizzled) ----
    const int lr  = ln & 15;
    const int lq  = ln >> 4;
    const int kof = (lq ^ ((lr >> 1) & 3)) << 4;               // byte offset of chunk
    const char* LAc = (const char*)As;
    const char* LBc = (const char*)Bs;
    const int aRd = wm * 64 + lr * 64 + kof;                   // wm*64: rows 64.. at +4K
    const int bRd = wn * 64 + lr * 64 + kof;

    f32x4 acc[4][4];
    #pragma unroll
    for (int i = 0; i < 4; ++i)
        #pragma unroll
        for (int j = 0; j < 4; ++j)
            acc[i][j] = (f32x4){0.f, 0.f, 0.f, 0.f};

#define STG(ks, k0)                                                                   \
    do {                                                                              \
        __builtin_amdgcn_global_load_lds((glb_t*)(aS + (k0) + (ks) * 32),             \
            (lds_t*)(laW + (ks) * 8192), 16, 0, 0);                                   \
        __builtin_amdgcn_global_load_lds((glb_t*)(aS + (size_t)64 * SD + (k0) + (ks) * 32), \
            (lds_t*)(laW + (ks) * 8192 + 4096), 16, 0, 0);                            \
        __builtin_amdgcn_global_load_lds((glb_t*)(bS + (k0) + (ks) * 32),             \
            (lds_t*)(lbW + (ks) * 8192), 16, 0, 0);                                   \
        __builtin_amdgcn_global_load_lds((glb_t*)(bS + (size_t)64 * SD + (k0) + (ks) * 32), \
            (lds_t*)(lbW + (ks) * 8192 + 4096), 16, 0, 0);                            \
    } while (0)

#define HALF(ks)                                                                      \
    do {                                                                              \
        short8 af[4], bq[4];                                                          \
        _Pragma("unroll")                                                             \
        for (int mt = 0; mt < 4; ++mt)                                                \
            af[mt] = *(const short8*)(LAc + (ks) * 8192 + mt * 1024 + aRd);           \
        _Pragma("unroll")                                                             \
        for (int nt = 0; nt < 4; ++nt)                                                \
            bq[nt] = *(const short8*)(LBc + (ks) * 8192 + nt * 1024 + bRd);           \
        _Pragma("unroll")                                                             \
        for (int mt = 0; mt < 4; ++mt)                                                \
            _Pragma("unroll")                                                         \
            for (int nt = 0; nt < 4; ++nt)                                            \
                acc[mt][nt] = __builtin_amdgcn_mfma_f32_16x16x32_bf16(                \
                    af[mt], bq[nt], acc[mt][nt], 0, 0, 0);                            \
    } while (0)

    for (int k0 = 0; k0 < SD; k0 += 64) {
        STG(0, k0);
        STG(1, k0);
        __syncthreads();   // compiler drains vmcnt(0) before s_barrier
        HALF(0);
        HALF(1);
        __syncthreads();
    }

#undef HALF
#undef STG

    // ---- epilogue: frag row = lq*4 + j, col = lr (m89-verified) ----
    const int cr = lq * 4;
    const int cc = lr;
    #pragma unroll
    for (int mt = 0; mt < 4; ++mt)
    #pragma unroll
    for (int nt = 0; nt < 4; ++nt) {
        const int gc = n0 + wn + nt * 16 + cc;
        const float bv = bias[gc];
        #pragma unroll
        for (int j = 0; j < 4; ++j) {
            const int gr = m0 + wm + mt * 16 + cr + j;
            float v = acc[mt][nt][j] + bv;
            if (FUSED == 1 || FUSED == 3) { if (dosig) v = 1.f / (1.f + __expf(-v)); }
            if (FUSED == 2)
                ((float*)Cout)[(size_t)gr * SD + gc] = v;
            else
                ((ushort*)Cout)[(size_t)gr * SD + gc] = f2bf(v);
        }
    }
}

// ---------------- scan pass 1: per-chunk local states from zero init ----------------
__global__ __launch_bounds__(256)
void scan_local(const ushort* __restrict__ kq, const ushort* __restrict__ vq,
                const float* __restrict__ td,
                float* __restrict__ sa, float* __restrict__ sb, float* __restrict__ sp)
{
    const int idx = blockIdx.x * 256 + threadIdx.x;   // 8192*NC
    const int ch = idx & (M_DIM - 1);
    const int c  = idx >> 13;
    const int b  = ch >> 10, d = ch & (SD - 1);
    const float w = -__expf(td[d]);
    size_t ptr = (size_t)b * U_DIM * SD + (size_t)(c * CT) * SD + d;

    float a = 0.f, bb = 0.f, p = -1e38f;
    for (int s = 0; s < CT; ++s) {
        const float kt = bf2f(kq[ptr]), vt = bf2f(vq[ptr]);
        const float q2 = fmaxf(p + w, kt);
        const float e1 = __expf(p + w - q2);
        const float e2 = __expf(kt - q2);
        a = e1 * a + e2 * vt; bb = e1 * bb + e2; p = q2;
        ptr += SD;
    }
    sa[idx] = a; sb[idx] = bb; sp[idx] = p;
}

// ---------------- scan pass 2: sequential prefix-combine over chunks ----------------
__global__ __launch_bounds__(256)
void scan_prefix(const float* __restrict__ td,
                 float* __restrict__ sa, float* __restrict__ sb, float* __restrict__ sp)
{
    const int ch = blockIdx.x * 256 + threadIdx.x;    // 8192
    const float wT = -__expf(td[ch & (SD - 1)]) * (float)CT;
    float ca = 0.f, cb = 0.f, cp = -1e38f;
    for (int c = 0; c < NC; ++c) {
        const int i = c * M_DIM + ch;
        const float la = sa[i], lb = sb[i], lp = sp[i];
        sa[i] = ca; sb[i] = cb; sp[i] = cp;
        const float pd = cp + wT;                      // decay carry across chunk
        const float q  = fmaxf(pd, lp);
        const float e1 = __expf(pd - q);
        const float e2 = __expf(lp - q);
        ca = e1 * ca + e2 * la; cb = e1 * cb + e2 * lb; cp = q;
    }
}

// ---------------- scan pass 3: outputs r*wkv (bf16) from incoming states ----------------
__global__ __launch_bounds__(256)
void scan_out(const ushort* __restrict__ kq, const ushort* __restrict__ vq,
              const ushort* __restrict__ rq,
              const float* __restrict__ td, const float* __restrict__ tfirst,
              const float* __restrict__ sa, const float* __restrict__ sb,
              const float* __restrict__ sp,
              ushort* __restrict__ rw)
{
    const int idx = blockIdx.x * 256 + threadIdx.x;
    const int ch = idx & (M_DIM - 1);
    const int c  = idx >> 13;
    const int b  = ch >> 10, d = ch & (SD - 1);
    const float w  = -__expf(td[d]);
    const float tf = tfirst[d];
    size_t ptr = (size_t)b * U_DIM * SD + (size_t)(c * CT) * SD + d;

    float a = sa[idx], bb = sb[idx], p = sp[idx];
    for (int s = 0; s < CT; ++s) {
        const float kt = bf2f(kq[ptr]), vt = bf2f(vq[ptr]), rt = bf2f(rq[ptr]);
        const float q  = fmaxf(p, tf + kt);
        const float e1 = __expf(p - q);
        const float e2 = __expf(tf + kt - q);
        const float ov = (e1 * a + e2 * vt) * __builtin_amdgcn_rcpf(e1 * bb + e2);
        const float q2  = fmaxf(p + w, kt);
        const float e1b = __expf(p + w - q2);
        const float e2b = __expf(kt - q2);
        a = e1b * a + e2b * vt; bb = e1b * bb + e2b; p = q2;
        rw[ptr] = f2bf(rt * ov);
        ptr += SD;
    }
}

extern "C" void kernel_launch(void* const* d_in, const int* in_sizes, int n_in,
                              void* d_out, int out_size, void* d_ws, size_t ws_size,
                              hipStream_t stream)
{
    (void)in_sizes; (void)n_in; (void)out_size;
    const float* x  = (const float*)d_in[0];
    const float* td = (const float*)d_in[1];
    const float* tf = (const float*)d_in[2];
    const float* mk = (const float*)d_in[3];
    const float* mv = (const float*)d_in[4];
    const float* mr = (const float*)d_in[5];
    const float* Wk = (const float*)d_in[6];
    const float* bk = (const float*)d_in[7];
    const float* Wv = (const float*)d_in[8];
    const float* bv = (const float*)d_in[9];
    const float* Wr = (const float*)d_in[10];
    const float* br = (const float*)d_in[11];
    const float* Wo = (const float*)d_in[12];
    const float* bo = (const float*)d_in[13];
    float* out = (float*)d_out;

    const size_t NE = (size_t)M_DIM * SD;   // 8M elements
    const size_t WS = (size_t)SD * SD;
    char* ws = (char*)d_ws;

    const dim3 gg1(64, 8, 1);
    const dim3 gg3(64, 24, 1);

    if (ws_size >= ((size_t)108 << 20)) {
        // fused layout: WT 0-8 | Ak 8-24 | Av 24-40 | Ar 40-56 | k 56-72 | v 72-88 |
        //               r 88-104 | states 104-107  (MB)
        ushort* WT  = (ushort*)ws;
        ushort* Ak  = (ushort*)(ws + ((size_t)8   << 20));
        ushort* kvr = (ushort*)(ws + ((size_t)56  << 20));
        float*  sa  = (float*)(ws + ((size_t)104 << 20));
        float*  sb  = (float*)(ws + ((size_t)105 << 20));
        float*  sp  = (float*)(ws + ((size_t)106 << 20));
        ushort* kbuf = kvr;
        ushort* vbuf = kvr + NE;
        ushort* rbuf = kvr + 2 * NE;
        ushort* rwkv = Ak;                  // A-buffers dead after proj GEMM

        wtrans_kernel<<<dim3(32, 32, 4), 256, 0, stream>>>(Wk, Wv, Wr, Wo, WT);
        mix3_kernel<<<8192, 256, 0, stream>>>(x, mk, mv, mr, Ak, Ak + NE, Ak + 2 * NE);
        gemm128<3><<<gg3, 256, 0, stream>>>(Ak, WT, bk, bv, br, kvr);

        scan_local <<<(M_DIM * NC) / 256, 256, 0, stream>>>(kbuf, vbuf, td, sa, sb, sp);
        scan_prefix<<<M_DIM / 256, 256, 0, stream>>>(td, sa, sb, sp);
        scan_out   <<<(M_DIM * NC) / 256, 256, 0, stream>>>(kbuf, vbuf, rbuf, td, tf,
                                                            sa, sb, sp, rwkv);

        gemm128<2><<<gg1, 256, 0, stream>>>(rwkv, WT + 3 * WS, bo, bo, bo, out);
    } else {
        // sequential layout (75 MB)
        ushort* WT   = (ushort*)ws;
        ushort* Abuf = (ushort*)(ws + ((size_t)8  << 20));
        ushort* kbuf = (ushort*)(ws + ((size_t)24 << 20));
        ushort* vbuf = (ushort*)(ws + ((size_t)40 << 20));
        ushort* rbuf = (ushort*)(ws + ((size_t)56 << 20));
        float*  sa   = (float*)(ws + ((size_t)72 << 20));
        float*  sb   = (float*)(ws + ((size_t)73 << 20));
        float*  sp   = (float*)(ws + ((size_t)74 << 20));
        ushort* rwkv = Abuf;

        wtrans_kernel<<<dim3(32, 32, 4), 256, 0, stream>>>(Wk, Wv, Wr, Wo, WT);
        mix_kernel<<<8192, 256, 0, stream>>>(x, mk, Abuf);
        gemm128<0><<<gg1, 256, 0, stream>>>(Abuf, WT, bk, bk, bk, kbuf);
        mix_kernel<<<8192, 256, 0, stream>>>(x, mv, Abuf);
        gemm128<0><<<gg1, 256, 0, stream>>>(Abuf, WT + WS, bv, bv, bv, vbuf);
        mix_kernel<<<8192, 256, 0, stream>>>(x, mr, Abuf);
        gemm128<1><<<gg1, 256, 0, stream>>>(Abuf, WT + 2 * WS, br, br, br, rbuf);

        scan_local <<<(M_DIM * NC) / 256, 256, 0, stream>>>(kbuf, vbuf, td, sa, sb, sp);
        scan_prefix<<<M_DIM / 256, 256, 0, stream>>>(td, sa, sb, sp);
        scan_out   <<<(M_DIM * NC) / 256, 256, 0, stream>>>(kbuf, vbuf, rbuf, td, tf,
                                                            sa, sb, sp, rwkv);

        gemm128<2><<<gg1, 256, 0, stream>>>(rwkv, WT + 3 * WS, bo, bo, bo, out);
    }
}